// Round 5
// baseline (370.672 us; speedup 1.0000x reference)
//
#include <hip/hip_runtime.h>

// KanLinear as one bf16 GEMM: out[b,o] = sum_k A[b,k]*W[k,o]
//   k <  1024: A = silu(x[b,k]),                      W = scale_base[k,o]
//   k >= 1024: A = exp(-((x[b,i]-grid[i,g])/sigma)^2), W = spline_w[o,i,g]*scale_spline[i,o]
// Round 5:
//  - Gemm BM 128->64: grid 1024 = 4 blocks/CU (was 2). r4: MfmaUtil 40% +
//    VALUBusy 29%, ~31% barrier drain; more resident blocks hide it (m114).
//  - All prep fused into ONE kernel (blockIdx branch): W-prep and A-prep are
//    independent -> now run concurrently. 2 launches total.
//  - Kept: XOR-swizzled LDS (conflicts=0), XCD block swizzle, hoisted addrs.

#define BATCH 8192
#define IN_F  1024
#define OUT_F 1024
#define GRID_N 8
#define KTOT  (IN_F + IN_F * GRID_N)   // 9216

#define BM 64
#define BN 128
#define BK 64

typedef __bf16 bf16x8 __attribute__((ext_vector_type(8)));
typedef float  f32x4  __attribute__((ext_vector_type(4)));

__device__ __forceinline__ void gl2lds16(const void* g, void* l) {
  __builtin_amdgcn_global_load_lds(
      (const __attribute__((address_space(1))) void*)g,
      (__attribute__((address_space(3))) void*)l, 16, 0, 0);
}

// ---------- fused prep ----------
// blocks [0,256):        base region of W: 64x64 LDS-transpose of scale_base
// blocks [256,4352):     spline region of W: wbt[o][1024+j] = sw*ss
// blocks [4352,12544):   A rows: Ab[b][k] = silu / RBF bases (b = blockIdx-4352)
__global__ __launch_bounds__(256)
void kan_prep(const float* __restrict__ sb, const float* __restrict__ sw,
              const float* __restrict__ ss, const float* __restrict__ x,
              const float* __restrict__ grid, const float* __restrict__ sigma,
              __bf16* __restrict__ wbt, __bf16* __restrict__ Ab) {
  const int t = threadIdx.x;
  if (blockIdx.x < 256) {
    __shared__ float tile[64][65];
    const int o0 = (blockIdx.x & 15) * 64, k0 = (blockIdx.x >> 4) * 64;
    const int r = t >> 4, c4 = (t & 15) * 4;
    #pragma unroll
    for (int it = 0; it < 4; ++it) {
      const int k = k0 + r + it * 16;
      float4 v = *(const float4*)(sb + (size_t)k * OUT_F + o0 + c4);
      tile[r + it * 16][c4 + 0] = v.x; tile[r + it * 16][c4 + 1] = v.y;
      tile[r + it * 16][c4 + 2] = v.z; tile[r + it * 16][c4 + 3] = v.w;
    }
    __syncthreads();
    #pragma unroll
    for (int it = 0; it < 4; ++it) {
      const int ol = r + it * 16;
      union { __bf16 h[4]; uint2 q; } s;
      #pragma unroll
      for (int e = 0; e < 4; ++e) s.h[e] = (__bf16)tile[c4 + e][ol];
      *(uint2*)(wbt + (size_t)(o0 + ol) * KTOT + k0 + c4) = s.q;
    }
  } else if (blockIdx.x < 4352) {
    const size_t e = ((size_t)(blockIdx.x - 256) * 256 + t) * 8;  // [0, 8.4M)
    const int o = (int)(e >> 13);
    const int j = (int)(e & 8191);
    const int i = j >> 3;
    const float sc = ss[(size_t)i * OUT_F + o];   // strided; one-touch, L2-absorbed
    float4 a = *(const float4*)(sw + e);
    float4 b = *(const float4*)(sw + e + 4);
    float vv[8] = {a.x, a.y, a.z, a.w, b.x, b.y, b.z, b.w};
    union { __bf16 h[8]; uint4 q; } s;
    #pragma unroll
    for (int g = 0; g < 8; ++g) s.h[g] = (__bf16)(vv[g] * sc);
    *(uint4*)(wbt + (size_t)o * KTOT + IN_F + j) = s.q;
  } else {
    const int b = blockIdx.x - 4352;
    const float inv_sigma = 1.0f / sigma[0];
    const float* xrow = x + (size_t)b * IN_F;
    __bf16* arow = Ab + (size_t)b * KTOT;
    {
      float4 v = ((const float4*)xrow)[t];
      float vv[4] = {v.x, v.y, v.z, v.w};
      union { __bf16 h[4]; uint2 q; } s;
      #pragma unroll
      for (int e = 0; e < 4; ++e) s.h[e] = (__bf16)(vv[e] / (1.0f + __expf(-vv[e])));
      ((uint2*)arow)[t] = s.q;
    }
    #pragma unroll
    for (int it = 0; it < 4; ++it) {
      const int i = t + it * 256;
      const float u = xrow[i];
      float4 g0 = *(const float4*)(grid + (size_t)i * GRID_N);
      float4 g1 = *(const float4*)(grid + (size_t)i * GRID_N + 4);
      float gg[8] = {g0.x, g0.y, g0.z, g0.w, g1.x, g1.y, g1.z, g1.w};
      union { __bf16 h[8]; uint4 q; } s;
      #pragma unroll
      for (int g = 0; g < GRID_N; ++g) {
        float d = (u - gg[g]) * inv_sigma;
        s.h[g] = (__bf16)__expf(-d * d);
      }
      *(uint4*)(arow + IN_F + (size_t)i * GRID_N) = s.q;
    }
  }
}

// ---------- GEMM: 64x128 tile, 4 blocks/CU, XOR-swizzled LDS, XCD swizzle ----------
__global__ __launch_bounds__(256)
void kan_gemm2(const __bf16* __restrict__ Ab, const __bf16* __restrict__ wbt,
               float* __restrict__ out) {
  __shared__ __bf16 As[BM * BK];   // 8 KB
  __shared__ __bf16 Bs[BN * BK];   // 16 KB
  const int tid = threadIdx.x;
  const int bx  = blockIdx.x;      // [0, 1024)
  // XCD swizzle: xcd = bx&7 owns row-tiles [xcd*16, xcd*16+16); the 8 blocks
  // sharing a row-tile are dispatch-adjacent on that XCD (A L2 reuse).
  const int s   = bx >> 3;                       // [0,128)
  const int r0  = ((bx & 7) * 16 + (s >> 3)) * BM;
  const int c0  = (s & 7) * BN;

  const int lane = tid & 63;
  const int wave = tid >> 6;
  const int wm = wave & 1, wn = wave >> 1;       // 2x2 waves over 64x128
  const int quad = lane >> 4, l15 = lane & 15;

  // Hoisted swizzled LDS element offsets (kb-invariant).
  int a_off[2][2], b_off[2][4];
  #pragma unroll
  for (int ks = 0; ks < 2; ++ks) {
    const int kc = ks * 4 + quad;
    #pragma unroll
    for (int t4 = 0; t4 < 2; ++t4) {
      const int rowA = wm * 32 + t4 * 16 + l15;
      a_off[ks][t4] = (rowA * 8 + (kc ^ (rowA & 7))) * 8;
    }
    #pragma unroll
    for (int t4 = 0; t4 < 4; ++t4) {
      const int rowB = wn * 64 + t4 * 16 + l15;
      b_off[ks][t4] = (rowB * 8 + (kc ^ (rowB & 7))) * 8;
    }
  }
  // Hoisted staging sources. As: 512 chunks (2 iters); Bs: 1024 chunks (4 iters).
  const __bf16* aSrc[2]; int aDst[2];
  #pragma unroll
  for (int it = 0; it < 2; ++it) {
    const int p16 = it * 256 + tid;
    const int row = p16 >> 3;
    const int kc  = (p16 & 7) ^ (row & 7);
    aSrc[it] = Ab + (size_t)(r0 + row) * KTOT + kc * 8;
    aDst[it] = p16 * 8;
  }
  const __bf16* bSrc[4]; int bDst[4];
  #pragma unroll
  for (int it = 0; it < 4; ++it) {
    const int p16 = it * 256 + tid;
    const int row = p16 >> 3;
    const int kc  = (p16 & 7) ^ (row & 7);
    bSrc[it] = wbt + (size_t)(c0 + row) * KTOT + kc * 8;
    bDst[it] = p16 * 8;
  }

  f32x4 zero; zero[0] = 0.f; zero[1] = 0.f; zero[2] = 0.f; zero[3] = 0.f;
  f32x4 acc[2][4];
  #pragma unroll
  for (int a = 0; a < 2; ++a)
    #pragma unroll
    for (int b = 0; b < 4; ++b) acc[a][b] = zero;

  for (int kb = 0; kb < KTOT; kb += BK) {
    __syncthreads();
    #pragma unroll
    for (int it = 0; it < 2; ++it) gl2lds16(aSrc[it] + kb, &As[aDst[it]]);
    #pragma unroll
    for (int it = 0; it < 4; ++it) gl2lds16(bSrc[it] + kb, &Bs[bDst[it]]);
    __syncthreads();
    #pragma unroll
    for (int ks = 0; ks < 2; ++ks) {
      bf16x8 af[2], bfv[4];
      #pragma unroll
      for (int t4 = 0; t4 < 2; ++t4) af[t4]  = *(const bf16x8*)&As[a_off[ks][t4]];
      #pragma unroll
      for (int t4 = 0; t4 < 4; ++t4) bfv[t4] = *(const bf16x8*)&Bs[b_off[ks][t4]];
      #pragma unroll
      for (int tm = 0; tm < 2; ++tm)
        #pragma unroll
        for (int tn = 0; tn < 4; ++tn)
          acc[tm][tn] = __builtin_amdgcn_mfma_f32_16x16x32_bf16(
              af[tm], bfv[tn], acc[tm][tn], 0, 0, 0);
    }
  }

  #pragma unroll
  for (int tm = 0; tm < 2; ++tm) {
    const int row = r0 + wm * 32 + tm * 16 + quad * 4;
    #pragma unroll
    for (int tn = 0; tn < 4; ++tn) {
      const int col = c0 + wn * 64 + tn * 16 + l15;
      float* op = out + (size_t)row * OUT_F + col;
      #pragma unroll
      for (int r = 0; r < 4; ++r)
        op[(size_t)r * OUT_F] = acc[tm][tn][r];
    }
  }
}

// ---------- fallback fused gemm (only if ws < 170MB; needs wbt only) ----------
__global__ __launch_bounds__(256, 2)
void kan_gemm(const float* __restrict__ x, const __bf16* __restrict__ wbt,
              const float* __restrict__ grid, const float* __restrict__ sigma,
              float* __restrict__ out) {
  __shared__ __bf16 As[128 * BK];
  __shared__ __bf16 Bs[128 * BK];
  __shared__ float  gLds[IN_F * GRID_N];
  const int tid = threadIdx.x;
  const int bx  = blockIdx.x;
  const int c0  = (bx & 7) * 128;
  const int r0  = (bx >> 3) * 128;
  for (int idx = tid; idx < IN_F * GRID_N / 4; idx += 256)
    ((float4*)gLds)[idx] = ((const float4*)grid)[idx];
  const float inv_sigma = 1.0f / sigma[0];
  const int lane = tid & 63;
  const int wave = tid >> 6;
  const int wm = wave & 1, wn = wave >> 1;
  const int quad = lane >> 4, l15 = lane & 15;
  f32x4 zero; zero[0] = 0.f; zero[1] = 0.f; zero[2] = 0.f; zero[3] = 0.f;
  f32x4 acc[4][4];
  #pragma unroll
  for (int a = 0; a < 4; ++a)
    #pragma unroll
    for (int b = 0; b < 4; ++b) acc[a][b] = zero;
  const int m = tid >> 1, half = tid & 1;
  const float* xrow = x + (size_t)(r0 + m) * IN_F;
  __syncthreads();
  for (int kb = 0; kb < KTOT; kb += BK) {
    union { __bf16 h[32]; uint4 q[4]; } av;
    if (kb < IN_F) {
      const float4* xp = (const float4*)(xrow + kb + half * 32);
      #pragma unroll
      for (int j4 = 0; j4 < 8; ++j4) {
        float4 v = xp[j4];
        float vv[4] = {v.x, v.y, v.z, v.w};
        #pragma unroll
        for (int e = 0; e < 4; ++e)
          av.h[j4 * 4 + e] = (__bf16)(vv[e] / (1.0f + __expf(-vv[e])));
      }
    } else {
      const int i0 = (kb - IN_F) >> 3;
      float4 xv = *(const float4*)(xrow + i0 + half * 4);
      float xs[4] = {xv.x, xv.y, xv.z, xv.w};
      #pragma unroll
      for (int ii = 0; ii < 4; ++ii) {
        const float u = xs[ii];
        const float* gp = &gLds[(i0 + half * 4 + ii) * GRID_N];
        #pragma unroll
        for (int g = 0; g < GRID_N; ++g) {
          float d = (u - gp[g]) * inv_sigma;
          av.h[ii * 8 + g] = (__bf16)__expf(-d * d);
        }
      }
    }
    __syncthreads();
    {
      uint4* dst = (uint4*)&As[m * BK + half * 32];
      #pragma unroll
      for (int qd = 0; qd < 4; ++qd) dst[qd] = av.q[qd];
    }
    #pragma unroll
    for (int it = 0; it < 4; ++it) {
      const int idx = it * 2048 + tid * 8;
      const int n = idx >> 6, k = idx & 63;
      gl2lds16(wbt + (size_t)(c0 + n) * KTOT + kb + k, &Bs[idx]);
    }
    __syncthreads();
    #pragma unroll
    for (int ks = 0; ks < 2; ++ks) {
      bf16x8 af[4], bfv[4];
      #pragma unroll
      for (int t4 = 0; t4 < 4; ++t4)
        af[t4] = *(const bf16x8*)&As[(wm * 64 + t4 * 16 + l15) * BK + ks * 32 + quad * 8];
      #pragma unroll
      for (int t4 = 0; t4 < 4; ++t4)
        bfv[t4] = *(const bf16x8*)&Bs[(wn * 64 + t4 * 16 + l15) * BK + ks * 32 + quad * 8];
      #pragma unroll
      for (int tm = 0; tm < 4; ++tm)
        #pragma unroll
        for (int tn = 0; tn < 4; ++tn)
          acc[tm][tn] = __builtin_amdgcn_mfma_f32_16x16x32_bf16(
              af[tm], bfv[tn], acc[tm][tn], 0, 0, 0);
    }
  }
  #pragma unroll
  for (int tm = 0; tm < 4; ++tm) {
    const int row = r0 + wm * 64 + tm * 16 + quad * 4;
    #pragma unroll
    for (int tn = 0; tn < 4; ++tn) {
      const int col = c0 + wn * 64 + tn * 16 + l15;
      float* op = out + (size_t)row * OUT_F + col;
      #pragma unroll
      for (int r = 0; r < 4; ++r)
        op[(size_t)r * OUT_F] = acc[tm][tn][r];
    }
  }
}

extern "C" void kernel_launch(void* const* d_in, const int* in_sizes, int n_in,
                              void* d_out, int out_size, void* d_ws, size_t ws_size,
                              hipStream_t stream) {
  const float* x     = (const float*)d_in[0];
  const float* sb    = (const float*)d_in[1];
  const float* sw    = (const float*)d_in[2];
  const float* ss    = (const float*)d_in[3];
  const float* grid  = (const float*)d_in[4];
  const float* sigma = (const float*)d_in[5];
  float* out = (float*)d_out;

  const size_t WBT_BYTES = (size_t)OUT_F * KTOT * 2;   // 18,874,368
  const size_t A_BYTES   = (size_t)BATCH * KTOT * 2;   // 150,994,944
  __bf16* wbt = (__bf16*)d_ws;

  if (ws_size >= WBT_BYTES + A_BYTES) {
    __bf16* Ab = (__bf16*)((char*)d_ws + WBT_BYTES);
    // one prep launch: 256 transpose + 4096 spline + 8192 A-row blocks
    kan_prep<<<dim3(4352 + BATCH), dim3(256), 0, stream>>>(
        sb, sw, ss, x, grid, sigma, wbt, Ab);
    kan_gemm2<<<dim3((BATCH / BM) * (OUT_F / BN)), dim3(256), 0, stream>>>(Ab, wbt, out);
  } else {
    // W-prep only (blocks < 4352 never touch Ab), then fused gemm
    kan_prep<<<dim3(4352), dim3(256), 0, stream>>>(
        sb, sw, ss, x, grid, sigma, wbt, (__bf16*)nullptr);
    kan_gemm<<<dim3((BATCH / 128) * (OUT_F / 128)), dim3(256), 0, stream>>>(
        x, wbt, grid, sigma, out);
  }
}

// Round 6
// 322.540 us; speedup vs baseline: 1.1492x; 1.1492x over previous
//
#include <hip/hip_runtime.h>

// KanLinear: out[b,o] = silu(x)@scale_base + bases@(spline_w*scale_spline)
// Round 6:
//  - Revert gemm tile to 128x128 (r5's 64x128 regressed: MfmaUtil 40->29,
//    FETCH 147->250MB; 128^2 is the measured sweet spot).
//  - Split base GEMM (K=1024, silu inline) from spline GEMM (K=8192) and run
//    the base GEMM CONCURRENTLY with all prep in one mixed launch; spline
//    GEMM accumulates (out +=) afterwards. Kernel-time model ~195us.
//  - Kept: XOR-swizzled LDS (conflicts=0), XCD block swizzle, hoisted addrs.

#define BATCH 8192
#define IN_F  1024
#define OUT_F 1024
#define GRID_N 8
#define K2    (IN_F * GRID_N)          // spline K = 8192
#define KTOT  (IN_F + K2)              // 9216 (fallback path)

#define BM 128
#define BN 128
#define BK 64

typedef __bf16 bf16x8 __attribute__((ext_vector_type(8)));
typedef float  f32x4  __attribute__((ext_vector_type(4)));

__device__ __forceinline__ void gl2lds16(const void* g, void* l) {
  __builtin_amdgcn_global_load_lds(
      (const __attribute__((address_space(1))) void*)g,
      (__attribute__((address_space(3))) void*)l, 16, 0, 0);
}

// ---------- launch 0: sbT[o][k] = (bf16)scale_base[k][o], stride 1024 ----------
__global__ __launch_bounds__(256)
void kan_transpose_sb(const float* __restrict__ sb, __bf16* __restrict__ sbT) {
  __shared__ float tile[64][65];
  const int o0 = (blockIdx.x & 15) * 64, k0 = (blockIdx.x >> 4) * 64;
  const int t = threadIdx.x;
  const int r = t >> 4, c4 = (t & 15) * 4;
  #pragma unroll
  for (int it = 0; it < 4; ++it) {
    const int k = k0 + r + it * 16;
    float4 v = *(const float4*)(sb + (size_t)k * OUT_F + o0 + c4);
    tile[r + it * 16][c4 + 0] = v.x; tile[r + it * 16][c4 + 1] = v.y;
    tile[r + it * 16][c4 + 2] = v.z; tile[r + it * 16][c4 + 3] = v.w;
  }
  __syncthreads();
  #pragma unroll
  for (int it = 0; it < 4; ++it) {
    const int ol = r + it * 16;
    union { __bf16 h[4]; uint2 q; } s;
    #pragma unroll
    for (int e = 0; e < 4; ++e) s.h[e] = (__bf16)tile[c4 + e][ol];
    *(uint2*)(sbT + (size_t)(o0 + ol) * IN_F + k0 + c4) = s.q;
  }
}

// ---------- launch 1: mixed {base GEMM | spline-W pack | bases-A build} ----------
// blocks [0,512):       base GEMM, K=1024, A=silu(x) inline, writes all of out
// blocks [512,4608):    wbt_s[o][j] = sw[o*8192+j] * ss[(j>>3)*1024+o]  (bf16)
// blocks [4608,12800):  Ab[b][i*8+g] = exp(-((x[b,i]-grid[i,g])/sigma)^2) (bf16)
__global__ __launch_bounds__(256)
void kan_mix(const float* __restrict__ x, const __bf16* __restrict__ sbT,
             const float* __restrict__ sw, const float* __restrict__ ss,
             const float* __restrict__ grid, const float* __restrict__ sigma,
             __bf16* __restrict__ wbt_s, __bf16* __restrict__ Ab,
             float* __restrict__ out) {
  __shared__ __bf16 As[BM * BK];   // 16 KB (base-gemm blocks only)
  __shared__ __bf16 Bs[BN * BK];   // 16 KB
  const int tid = threadIdx.x;
  const int bx  = blockIdx.x;

  if (bx < 512) {
    // ---- base GEMM: C = silu(x) @ sbT^T, 128x128 tile, 16 K-iters ----
    const int s  = bx >> 3;
    const int r0 = ((bx & 7) * 8 + (s >> 3)) * BM;
    const int c0 = (s & 7) * BN;
    const int lane = tid & 63, wave = tid >> 6;
    const int wm = wave & 1, wn = wave >> 1;
    const int quad = lane >> 4, l15 = lane & 15;

    int a_off[2][4], b_off[2][4];
    #pragma unroll
    for (int ks = 0; ks < 2; ++ks) {
      const int kc = ks * 4 + quad;
      #pragma unroll
      for (int t4 = 0; t4 < 4; ++t4) {
        const int rowA = wm * 64 + t4 * 16 + l15;
        a_off[ks][t4] = (rowA * 8 + (kc ^ (rowA & 7))) * 8;
        const int rowB = wn * 64 + t4 * 16 + l15;
        b_off[ks][t4] = (rowB * 8 + (kc ^ (rowB & 7))) * 8;
      }
    }
    const __bf16* bSrc[4]; int bDst[4];
    #pragma unroll
    for (int it = 0; it < 4; ++it) {
      const int p16 = it * 256 + tid;
      const int row = p16 >> 3;
      const int kc  = (p16 & 7) ^ (row & 7);
      bSrc[it] = sbT + (size_t)(c0 + row) * IN_F + kc * 8;
      bDst[it] = p16 * 8;
    }
    // A-fill mapping: thread -> row m, half of the 64-wide k-block
    const int m = tid >> 1, half = tid & 1;
    const float* xrow = x + (size_t)(r0 + m) * IN_F;
    // swizzled ds_write chunks (kb-invariant)
    int aw_off[4];
    #pragma unroll
    for (int q = 0; q < 4; ++q)
      aw_off[q] = (m * 8 + ((half * 4 + q) ^ (m & 7))) * 8;

    f32x4 zero; zero[0] = 0.f; zero[1] = 0.f; zero[2] = 0.f; zero[3] = 0.f;
    f32x4 acc[4][4];
    #pragma unroll
    for (int a = 0; a < 4; ++a)
      #pragma unroll
      for (int b = 0; b < 4; ++b) acc[a][b] = zero;

    for (int kb = 0; kb < IN_F; kb += BK) {
      union { __bf16 h[32]; uint4 q[4]; } av;
      const float4* xp = (const float4*)(xrow + kb + half * 32);
      #pragma unroll
      for (int j4 = 0; j4 < 8; ++j4) {
        float4 v = xp[j4];
        float vv[4] = {v.x, v.y, v.z, v.w};
        #pragma unroll
        for (int e = 0; e < 4; ++e)
          av.h[j4 * 4 + e] = (__bf16)(vv[e] / (1.0f + __expf(-vv[e])));
      }
      __syncthreads();
      #pragma unroll
      for (int q = 0; q < 4; ++q)
        *(uint4*)&As[aw_off[q]] = av.q[q];
      #pragma unroll
      for (int it = 0; it < 4; ++it)
        gl2lds16(bSrc[it] + kb, &Bs[bDst[it]]);
      __syncthreads();
      #pragma unroll
      for (int ks = 0; ks < 2; ++ks) {
        bf16x8 af[4], bfv[4];
        #pragma unroll
        for (int t4 = 0; t4 < 4; ++t4) af[t4]  = *(const bf16x8*)&As[a_off[ks][t4]];
        #pragma unroll
        for (int t4 = 0; t4 < 4; ++t4) bfv[t4] = *(const bf16x8*)&Bs[b_off[ks][t4]];
        #pragma unroll
        for (int tm = 0; tm < 4; ++tm)
          #pragma unroll
          for (int tn = 0; tn < 4; ++tn)
            acc[tm][tn] = __builtin_amdgcn_mfma_f32_16x16x32_bf16(
                af[tm], bfv[tn], acc[tm][tn], 0, 0, 0);
      }
    }
    #pragma unroll
    for (int tm = 0; tm < 4; ++tm) {
      const int row = r0 + wm * 64 + tm * 16 + quad * 4;
      #pragma unroll
      for (int tn = 0; tn < 4; ++tn) {
        const int col = c0 + wn * 64 + tn * 16 + l15;
        float* op = out + (size_t)row * OUT_F + col;
        #pragma unroll
        for (int r = 0; r < 4; ++r)
          op[(size_t)r * OUT_F] = acc[tm][tn][r];
      }
    }
  } else if (bx < 4608) {
    // ---- spline-W pack ----
    const size_t e = ((size_t)(bx - 512) * 256 + tid) * 8;  // [0, 8.4M)
    const int o = (int)(e >> 13);
    const int j = (int)(e & 8191);
    const int i = j >> 3;
    const float sc = ss[(size_t)i * OUT_F + o];
    float4 a = *(const float4*)(sw + e);
    float4 b = *(const float4*)(sw + e + 4);
    float vv[8] = {a.x, a.y, a.z, a.w, b.x, b.y, b.z, b.w};
    union { __bf16 h[8]; uint4 q; } s;
    #pragma unroll
    for (int g = 0; g < 8; ++g) s.h[g] = (__bf16)(vv[g] * sc);
    *(uint4*)(wbt_s + (size_t)o * K2 + j) = s.q;
  } else {
    // ---- bases-A build ----
    const int b = bx - 4608;
    const float inv_sigma = 1.0f / sigma[0];
    const float* xrow = x + (size_t)b * IN_F;
    __bf16* arow = Ab + (size_t)b * K2;
    #pragma unroll
    for (int it = 0; it < 4; ++it) {
      const int i = tid + it * 256;
      const float u = xrow[i];
      float4 g0 = *(const float4*)(grid + (size_t)i * GRID_N);
      float4 g1 = *(const float4*)(grid + (size_t)i * GRID_N + 4);
      float gg[8] = {g0.x, g0.y, g0.z, g0.w, g1.x, g1.y, g1.z, g1.w};
      union { __bf16 h[8]; uint4 q; } s;
      #pragma unroll
      for (int g = 0; g < GRID_N; ++g) {
        float d = (u - gg[g]) * inv_sigma;
        s.h[g] = (__bf16)__expf(-d * d);
      }
      *(uint4*)(arow + (size_t)i * GRID_N) = s.q;
    }
  }
}

// ---------- launch 2: spline GEMM (K=8192), out += Ab @ wbt_s^T ----------
__global__ __launch_bounds__(256)
void kan_gemm_spline(const __bf16* __restrict__ Ab, const __bf16* __restrict__ wbt_s,
                     float* __restrict__ out) {
  __shared__ __bf16 As[BM * BK];
  __shared__ __bf16 Bs[BN * BK];
  const int tid = threadIdx.x;
  const int bx  = blockIdx.x;
  const int s   = bx >> 3;
  const int r0  = ((bx & 7) * 8 + (s >> 3)) * BM;
  const int c0  = (s & 7) * BN;

  const int lane = tid & 63, wave = tid >> 6;
  const int wm = wave & 1, wn = wave >> 1;
  const int quad = lane >> 4, l15 = lane & 15;

  int a_off[2][4], b_off[2][4];
  #pragma unroll
  for (int ks = 0; ks < 2; ++ks) {
    const int kc = ks * 4 + quad;
    #pragma unroll
    for (int t4 = 0; t4 < 4; ++t4) {
      const int rowA = wm * 64 + t4 * 16 + l15;
      a_off[ks][t4] = (rowA * 8 + (kc ^ (rowA & 7))) * 8;
      const int rowB = wn * 64 + t4 * 16 + l15;
      b_off[ks][t4] = (rowB * 8 + (kc ^ (rowB & 7))) * 8;
    }
  }
  const __bf16* aSrc[4]; const __bf16* bSrc[4]; int dstOff[4];
  #pragma unroll
  for (int it = 0; it < 4; ++it) {
    const int p16 = it * 256 + tid;
    const int row = p16 >> 3;
    const int kc  = (p16 & 7) ^ (row & 7);
    aSrc[it] = Ab    + (size_t)(r0 + row) * K2 + kc * 8;
    bSrc[it] = wbt_s + (size_t)(c0 + row) * K2 + kc * 8;
    dstOff[it] = p16 * 8;
  }

  f32x4 zero; zero[0] = 0.f; zero[1] = 0.f; zero[2] = 0.f; zero[3] = 0.f;
  f32x4 acc[4][4];
  #pragma unroll
  for (int a = 0; a < 4; ++a)
    #pragma unroll
    for (int b = 0; b < 4; ++b) acc[a][b] = zero;

  for (int kb = 0; kb < K2; kb += BK) {
    __syncthreads();
    #pragma unroll
    for (int it = 0; it < 4; ++it) {
      gl2lds16(aSrc[it] + kb, &As[dstOff[it]]);
      gl2lds16(bSrc[it] + kb, &Bs[dstOff[it]]);
    }
    __syncthreads();
    #pragma unroll
    for (int ks = 0; ks < 2; ++ks) {
      bf16x8 af[4], bfv[4];
      #pragma unroll
      for (int t4 = 0; t4 < 4; ++t4) af[t4]  = *(const bf16x8*)&As[a_off[ks][t4]];
      #pragma unroll
      for (int t4 = 0; t4 < 4; ++t4) bfv[t4] = *(const bf16x8*)&Bs[b_off[ks][t4]];
      #pragma unroll
      for (int tm = 0; tm < 4; ++tm)
        #pragma unroll
        for (int tn = 0; tn < 4; ++tn)
          acc[tm][tn] = __builtin_amdgcn_mfma_f32_16x16x32_bf16(
              af[tm], bfv[tn], acc[tm][tn], 0, 0, 0);
    }
  }

  #pragma unroll
  for (int tm = 0; tm < 4; ++tm) {
    const int row = r0 + wm * 64 + tm * 16 + quad * 4;
    #pragma unroll
    for (int tn = 0; tn < 4; ++tn) {
      const int col = c0 + wn * 64 + tn * 16 + l15;
      float* op = out + (size_t)row * OUT_F + col;
      #pragma unroll
      for (int r = 0; r < 4; ++r)
        op[(size_t)r * OUT_F] += acc[tm][tn][r];   // accumulate onto base result
    }
  }
}

// ---------- fallback path (ws too small): full-W prep + fused gemm ----------
__global__ __launch_bounds__(256)
void kan_prep_w_full(const float* __restrict__ sb, const float* __restrict__ sw,
                     const float* __restrict__ ss, __bf16* __restrict__ wbt) {
  const int t = threadIdx.x;
  if (blockIdx.x < 256) {
    __shared__ float tile[64][65];
    const int o0 = (blockIdx.x & 15) * 64, k0 = (blockIdx.x >> 4) * 64;
    const int r = t >> 4, c4 = (t & 15) * 4;
    #pragma unroll
    for (int it = 0; it < 4; ++it) {
      const int k = k0 + r + it * 16;
      float4 v = *(const float4*)(sb + (size_t)k * OUT_F + o0 + c4);
      tile[r + it * 16][c4 + 0] = v.x; tile[r + it * 16][c4 + 1] = v.y;
      tile[r + it * 16][c4 + 2] = v.z; tile[r + it * 16][c4 + 3] = v.w;
    }
    __syncthreads();
    #pragma unroll
    for (int it = 0; it < 4; ++it) {
      const int ol = r + it * 16;
      union { __bf16 h[4]; uint2 q; } s;
      #pragma unroll
      for (int e = 0; e < 4; ++e) s.h[e] = (__bf16)tile[c4 + e][ol];
      *(uint2*)(wbt + (size_t)(o0 + ol) * KTOT + k0 + c4) = s.q;
    }
  } else {
    const size_t e = ((size_t)(blockIdx.x - 256) * 256 + t) * 8;
    const int o = (int)(e >> 13);
    const int j = (int)(e & 8191);
    const int i = j >> 3;
    const float sc = ss[(size_t)i * OUT_F + o];
    float4 a = *(const float4*)(sw + e);
    float4 b = *(const float4*)(sw + e + 4);
    float vv[8] = {a.x, a.y, a.z, a.w, b.x, b.y, b.z, b.w};
    union { __bf16 h[8]; uint4 q; } s;
    #pragma unroll
    for (int g = 0; g < 8; ++g) s.h[g] = (__bf16)(vv[g] * sc);
    *(uint4*)(wbt + (size_t)o * KTOT + IN_F + j) = s.q;
  }
}

__global__ __launch_bounds__(256, 2)
void kan_gemm_fused(const float* __restrict__ x, const __bf16* __restrict__ wbt,
                    const float* __restrict__ grid, const float* __restrict__ sigma,
                    float* __restrict__ out) {
  __shared__ __bf16 As[BM * BK];
  __shared__ __bf16 Bs[BN * BK];
  __shared__ float  gLds[IN_F * GRID_N];
  const int tid = threadIdx.x;
  const int bx  = blockIdx.x;
  const int c0  = (bx & 7) * BN;
  const int r0  = (bx >> 3) * BM;
  for (int idx = tid; idx < IN_F * GRID_N / 4; idx += 256)
    ((float4*)gLds)[idx] = ((const float4*)grid)[idx];
  const float inv_sigma = 1.0f / sigma[0];
  const int lane = tid & 63, wave = tid >> 6;
  const int wm = wave & 1, wn = wave >> 1;
  const int quad = lane >> 4, l15 = lane & 15;
  f32x4 zero; zero[0] = 0.f; zero[1] = 0.f; zero[2] = 0.f; zero[3] = 0.f;
  f32x4 acc[4][4];
  #pragma unroll
  for (int a = 0; a < 4; ++a)
    #pragma unroll
    for (int b = 0; b < 4; ++b) acc[a][b] = zero;
  const int m = tid >> 1, half = tid & 1;
  const float* xrow = x + (size_t)(r0 + m) * IN_F;
  __syncthreads();
  for (int kb = 0; kb < KTOT; kb += BK) {
    union { __bf16 h[32]; uint4 q[4]; } av;
    if (kb < IN_F) {
      const float4* xp = (const float4*)(xrow + kb + half * 32);
      #pragma unroll
      for (int j4 = 0; j4 < 8; ++j4) {
        float4 v = xp[j4];
        float vv[4] = {v.x, v.y, v.z, v.w};
        #pragma unroll
        for (int e = 0; e < 4; ++e)
          av.h[j4 * 4 + e] = (__bf16)(vv[e] / (1.0f + __expf(-vv[e])));
      }
    } else {
      const int i0 = (kb - IN_F) >> 3;
      float4 xv = *(const float4*)(xrow + i0 + half * 4);
      float xs[4] = {xv.x, xv.y, xv.z, xv.w};
      #pragma unroll
      for (int ii = 0; ii < 4; ++ii) {
        const float u = xs[ii];
        const float* gp = &gLds[(i0 + half * 4 + ii) * GRID_N];
        #pragma unroll
        for (int g = 0; g < GRID_N; ++g) {
          float d = (u - gp[g]) * inv_sigma;
          av.h[ii * 8 + g] = (__bf16)__expf(-d * d);
        }
      }
    }
    __syncthreads();
    {
      uint4* dst = (uint4*)&As[m * BK + half * 32];
      #pragma unroll
      for (int qd = 0; qd < 4; ++qd) dst[qd] = av.q[qd];
    }
    #pragma unroll
    for (int it = 0; it < 4; ++it) {
      const int idx = it * 2048 + tid * 8;
      const int n = idx >> 6, k = idx & 63;
      gl2lds16(wbt + (size_t)(c0 + n) * KTOT + kb + k, &Bs[idx]);
    }
    __syncthreads();
    #pragma unroll
    for (int ks = 0; ks < 2; ++ks) {
      bf16x8 af[4], bfv[4];
      #pragma unroll
      for (int t4 = 0; t4 < 4; ++t4)
        af[t4] = *(const bf16x8*)&As[(wm * 64 + t4 * 16 + l15) * BK + ks * 32 + quad * 8];
      #pragma unroll
      for (int t4 = 0; t4 < 4; ++t4)
        bfv[t4] = *(const bf16x8*)&Bs[(wn * 64 + t4 * 16 + l15) * BK + ks * 32 + quad * 8];
      #pragma unroll
      for (int tm = 0; tm < 4; ++tm)
        #pragma unroll
        for (int tn = 0; tn < 4; ++tn)
          acc[tm][tn] = __builtin_amdgcn_mfma_f32_16x16x32_bf16(
              af[tm], bfv[tn], acc[tm][tn], 0, 0, 0);
    }
  }
  #pragma unroll
  for (int tm = 0; tm < 4; ++tm) {
    const int row = r0 + wm * 64 + tm * 16 + quad * 4;
    #pragma unroll
    for (int tn = 0; tn < 4; ++tn) {
      const int col = c0 + wn * 64 + tn * 16 + l15;
      float* op = out + (size_t)row * OUT_F + col;
      #pragma unroll
      for (int r = 0; r < 4; ++r)
        op[(size_t)r * OUT_F] = acc[tm][tn][r];
    }
  }
}

extern "C" void kernel_launch(void* const* d_in, const int* in_sizes, int n_in,
                              void* d_out, int out_size, void* d_ws, size_t ws_size,
                              hipStream_t stream) {
  const float* x     = (const float*)d_in[0];
  const float* sb    = (const float*)d_in[1];
  const float* sw    = (const float*)d_in[2];
  const float* ss    = (const float*)d_in[3];
  const float* grid  = (const float*)d_in[4];
  const float* sigma = (const float*)d_in[5];
  float* out = (float*)d_out;

  const size_t SBT_BYTES = (size_t)OUT_F * IN_F * 2;   //   2 MB
  const size_t WS_BYTES  = (size_t)OUT_F * K2 * 2;     //  16.8 MB
  const size_t A_BYTES   = (size_t)BATCH * K2 * 2;     // 134.2 MB
  // total needed: ~153 MB

  if (ws_size >= SBT_BYTES + WS_BYTES + A_BYTES) {
    __bf16* sbT   = (__bf16*)d_ws;
    __bf16* wbt_s = (__bf16*)((char*)d_ws + SBT_BYTES);
    __bf16* Ab    = (__bf16*)((char*)d_ws + SBT_BYTES + WS_BYTES);
    kan_transpose_sb<<<dim3(256), dim3(256), 0, stream>>>(sb, sbT);
    kan_mix<<<dim3(512 + 4096 + BATCH), dim3(256), 0, stream>>>(
        x, sbT, sw, ss, grid, sigma, wbt_s, Ab, out);
    kan_gemm_spline<<<dim3((BATCH / BM) * (OUT_F / BN)), dim3(256), 0, stream>>>(
        Ab, wbt_s, out);
  } else {
    __bf16* wbt = (__bf16*)d_ws;   // 18.9 MB
    kan_prep_w_full<<<dim3(4352), dim3(256), 0, stream>>>(sb, sw, ss, wbt);
    kan_gemm_fused<<<dim3((BATCH / BM) * (OUT_F / BN)), dim3(256), 0, stream>>>(
        x, wbt, grid, sigma, out);
  }
}

// Round 7
// 265.292 us; speedup vs baseline: 1.3972x; 1.2158x over previous
//
#include <hip/hip_runtime.h>

// KanLinear: out[b,o] = silu(x)@scale_base + bases@(spline_w*scale_spline)
// Round 7: spline GEMM -> MX-fp8 (e4m3, unit scales) via
// mfma_scale_f32_16x16x128_f8f6f4: measured 1.86x over bf16 on this exact
// structure (m148: 874->1628 TF). Spline terms are tiny (|sum|~0.4) so fp8
// noise << threshold; base GEMM stays bf16 (it carries the ~300 magnitude).
// A-bases and W-spline packed as fp8 (halves prep write + gemm fetch).
// Kept: 128x128 tiles, XOR-swizzled LDS (conflicts=0), XCD swizzle, out+=.

#define BATCH 8192
#define IN_F  1024
#define OUT_F 1024
#define GRID_N 8
#define K2    (IN_F * GRID_N)          // spline K = 8192
#define KTOT  (IN_F + K2)              // 9216 (fallback path)

#define BM 128
#define BN 128
#define BK 64        // bf16 k-tile (base gemm / fallback)
#define BK8 128      // fp8 k-tile (bytes)

typedef __bf16 bf16x8 __attribute__((ext_vector_type(8)));
typedef float  f32x4  __attribute__((ext_vector_type(4)));
typedef int    int32x8 __attribute__((ext_vector_type(8)));

__device__ __forceinline__ void gl2lds16(const void* g, void* l) {
  __builtin_amdgcn_global_load_lds(
      (const __attribute__((address_space(1))) void*)g,
      (__attribute__((address_space(3))) void*)l, 16, 0, 0);
}

// pack 8 floats -> 8 fp8 e4m3 bytes (two i32 words)
__device__ __forceinline__ void pack_fp8x8(const float* v, int& w0, int& w1) {
  w0 = 0; w1 = 0;
  w0 = __builtin_amdgcn_cvt_pk_fp8_f32(v[0], v[1], w0, false);
  w0 = __builtin_amdgcn_cvt_pk_fp8_f32(v[2], v[3], w0, true);
  w1 = __builtin_amdgcn_cvt_pk_fp8_f32(v[4], v[5], w1, false);
  w1 = __builtin_amdgcn_cvt_pk_fp8_f32(v[6], v[7], w1, true);
}

// ---------- launch 0: sbT[o][k] = (bf16)scale_base[k][o] ----------
__global__ __launch_bounds__(256)
void kan_transpose_sb(const float* __restrict__ sb, __bf16* __restrict__ sbT) {
  __shared__ float tile[64][65];
  const int o0 = (blockIdx.x & 15) * 64, k0 = (blockIdx.x >> 4) * 64;
  const int t = threadIdx.x;
  const int r = t >> 4, c4 = (t & 15) * 4;
  #pragma unroll
  for (int it = 0; it < 4; ++it) {
    const int k = k0 + r + it * 16;
    float4 v = *(const float4*)(sb + (size_t)k * OUT_F + o0 + c4);
    tile[r + it * 16][c4 + 0] = v.x; tile[r + it * 16][c4 + 1] = v.y;
    tile[r + it * 16][c4 + 2] = v.z; tile[r + it * 16][c4 + 3] = v.w;
  }
  __syncthreads();
  #pragma unroll
  for (int it = 0; it < 4; ++it) {
    const int ol = r + it * 16;
    union { __bf16 h[4]; uint2 q; } s;
    #pragma unroll
    for (int e = 0; e < 4; ++e) s.h[e] = (__bf16)tile[c4 + e][ol];
    *(uint2*)(sbT + (size_t)(o0 + ol) * IN_F + k0 + c4) = s.q;
  }
}

// ---------- launch 1: mixed {base GEMM bf16 | spline-W fp8 | bases-A fp8} ----------
__global__ __launch_bounds__(256)
void kan_mix(const float* __restrict__ x, const __bf16* __restrict__ sbT,
             const float* __restrict__ sw, const float* __restrict__ ss,
             const float* __restrict__ grid, const float* __restrict__ sigma,
             unsigned char* __restrict__ wbt8, unsigned char* __restrict__ Ab8,
             float* __restrict__ out) {
  __shared__ __bf16 As[BM * BK];
  __shared__ __bf16 Bs[BN * BK];
  const int tid = threadIdx.x;
  const int bx  = blockIdx.x;

  if (bx < 512) {
    // ---- base GEMM: C = silu(x) @ sbT^T, 128x128 tile, K=1024 ----
    const int s  = bx >> 3;
    const int r0 = ((bx & 7) * 8 + (s >> 3)) * BM;
    const int c0 = (s & 7) * BN;
    const int lane = tid & 63, wave = tid >> 6;
    const int wm = wave & 1, wn = wave >> 1;
    const int quad = lane >> 4, l15 = lane & 15;

    int a_off[2][4], b_off[2][4];
    #pragma unroll
    for (int ks = 0; ks < 2; ++ks) {
      const int kc = ks * 4 + quad;
      #pragma unroll
      for (int t4 = 0; t4 < 4; ++t4) {
        const int rowA = wm * 64 + t4 * 16 + l15;
        a_off[ks][t4] = (rowA * 8 + (kc ^ (rowA & 7))) * 8;
        const int rowB = wn * 64 + t4 * 16 + l15;
        b_off[ks][t4] = (rowB * 8 + (kc ^ (rowB & 7))) * 8;
      }
    }
    const __bf16* bSrc[4]; int bDst[4];
    #pragma unroll
    for (int it = 0; it < 4; ++it) {
      const int p16 = it * 256 + tid;
      const int row = p16 >> 3;
      const int kc  = (p16 & 7) ^ (row & 7);
      bSrc[it] = sbT + (size_t)(c0 + row) * IN_F + kc * 8;
      bDst[it] = p16 * 8;
    }
    const int m = tid >> 1, half = tid & 1;
    const float* xrow = x + (size_t)(r0 + m) * IN_F;
    int aw_off[4];
    #pragma unroll
    for (int q = 0; q < 4; ++q)
      aw_off[q] = (m * 8 + ((half * 4 + q) ^ (m & 7))) * 8;

    f32x4 zero; zero[0] = 0.f; zero[1] = 0.f; zero[2] = 0.f; zero[3] = 0.f;
    f32x4 acc[4][4];
    #pragma unroll
    for (int a = 0; a < 4; ++a)
      #pragma unroll
      for (int b = 0; b < 4; ++b) acc[a][b] = zero;

    for (int kb = 0; kb < IN_F; kb += BK) {
      union { __bf16 h[32]; uint4 q[4]; } av;
      const float4* xp = (const float4*)(xrow + kb + half * 32);
      #pragma unroll
      for (int j4 = 0; j4 < 8; ++j4) {
        float4 v = xp[j4];
        float vv[4] = {v.x, v.y, v.z, v.w};
        #pragma unroll
        for (int e = 0; e < 4; ++e)
          av.h[j4 * 4 + e] = (__bf16)(vv[e] / (1.0f + __expf(-vv[e])));
      }
      __syncthreads();
      #pragma unroll
      for (int q = 0; q < 4; ++q)
        *(uint4*)&As[aw_off[q]] = av.q[q];
      #pragma unroll
      for (int it = 0; it < 4; ++it)
        gl2lds16(bSrc[it] + kb, &Bs[bDst[it]]);
      __syncthreads();
      #pragma unroll
      for (int ks = 0; ks < 2; ++ks) {
        bf16x8 af[4], bfv[4];
        #pragma unroll
        for (int t4 = 0; t4 < 4; ++t4) af[t4]  = *(const bf16x8*)&As[a_off[ks][t4]];
        #pragma unroll
        for (int t4 = 0; t4 < 4; ++t4) bfv[t4] = *(const bf16x8*)&Bs[b_off[ks][t4]];
        #pragma unroll
        for (int tm = 0; tm < 4; ++tm)
          #pragma unroll
          for (int tn = 0; tn < 4; ++tn)
            acc[tm][tn] = __builtin_amdgcn_mfma_f32_16x16x32_bf16(
                af[tm], bfv[tn], acc[tm][tn], 0, 0, 0);
      }
    }
    #pragma unroll
    for (int tm = 0; tm < 4; ++tm) {
      const int row = r0 + wm * 64 + tm * 16 + quad * 4;
      #pragma unroll
      for (int tn = 0; tn < 4; ++tn) {
        const int col = c0 + wn * 64 + tn * 16 + l15;
        float* op = out + (size_t)row * OUT_F + col;
        #pragma unroll
        for (int r = 0; r < 4; ++r)
          op[(size_t)r * OUT_F] = acc[tm][tn][r];
      }
    }
  } else if (bx < 4608) {
    // ---- spline-W pack (fp8): wbt8[o][j] = fp8(sw[o*8192+j] * ss[(j>>3)*1024+o])
    const size_t e = ((size_t)(bx - 512) * 256 + tid) * 8;
    const int o = (int)(e >> 13);
    const int j = (int)(e & 8191);
    const int i = j >> 3;
    const float sc = ss[(size_t)i * OUT_F + o];
    float4 a = *(const float4*)(sw + e);
    float4 b = *(const float4*)(sw + e + 4);
    float vv[8] = {a.x * sc, a.y * sc, a.z * sc, a.w * sc,
                   b.x * sc, b.y * sc, b.z * sc, b.w * sc};
    int w0, w1; pack_fp8x8(vv, w0, w1);
    *(int2*)(wbt8 + (size_t)o * K2 + j) = make_int2(w0, w1);
  } else {
    // ---- bases-A build (fp8): Ab8[b][i*8+g] = fp8(exp(-((x-g)/sigma)^2))
    const int b = bx - 4608;
    const float inv_sigma = 1.0f / sigma[0];
    const float* xrow = x + (size_t)b * IN_F;
    unsigned char* arow = Ab8 + (size_t)b * K2;
    #pragma unroll
    for (int it = 0; it < 4; ++it) {
      const int i = tid + it * 256;
      const float u = xrow[i];
      float4 g0 = *(const float4*)(grid + (size_t)i * GRID_N);
      float4 g1 = *(const float4*)(grid + (size_t)i * GRID_N + 4);
      float gg[8] = {g0.x, g0.y, g0.z, g0.w, g1.x, g1.y, g1.z, g1.w};
      float bb[8];
      #pragma unroll
      for (int g = 0; g < GRID_N; ++g) {
        float d = (u - gg[g]) * inv_sigma;
        bb[g] = __expf(-d * d);
      }
      int w0, w1; pack_fp8x8(bb, w0, w1);
      *(int2*)(arow + (size_t)i * GRID_N) = make_int2(w0, w1);
    }
  }
}

// ---------- launch 2: fp8 MX spline GEMM (K=8192), out += A8 @ W8^T ----------
__global__ __launch_bounds__(256)
void kan_gemm_spline_fp8(const unsigned char* __restrict__ Ab8,
                         const unsigned char* __restrict__ wbt8,
                         float* __restrict__ out) {
  __shared__ unsigned char As[BM * BK8];   // 16 KB (128 rows x 128 bytes)
  __shared__ unsigned char Bs[BN * BK8];   // 16 KB
  const int tid = threadIdx.x;
  const int bx  = blockIdx.x;
  const int s   = bx >> 3;
  const int r0  = ((bx & 7) * 8 + (s >> 3)) * BM;
  const int c0  = (s & 7) * BN;

  const int lane = tid & 63, wave = tid >> 6;
  const int wm = wave & 1, wn = wave >> 1;
  const int quad = lane >> 4, l15 = lane & 15;

  // Hoisted swizzled LDS byte offsets: lane reads 32B = chunks {quad*2, quad*2+1}
  // of its row, each XORed with row&7. (kb-invariant)
  int a_off[4][2], b_off[4][2];
  #pragma unroll
  for (int t4 = 0; t4 < 4; ++t4) {
    const int rowA = wm * 64 + t4 * 16 + l15;
    const int rowB = wn * 64 + t4 * 16 + l15;
    #pragma unroll
    for (int h = 0; h < 2; ++h) {
      a_off[t4][h] = rowA * BK8 + (((quad * 2 + h) ^ (rowA & 7)) * 16);
      b_off[t4][h] = rowB * BK8 + (((quad * 2 + h) ^ (rowB & 7)) * 16);
    }
  }
  // Hoisted staging: 1024 chunks per tile = 4 iters x 256 lanes, 16B each.
  const unsigned char* aSrc[4]; const unsigned char* bSrc[4]; int dstOff[4];
  #pragma unroll
  for (int it = 0; it < 4; ++it) {
    const int p16 = it * 256 + tid;
    const int row = p16 >> 3;
    const int kc  = (p16 & 7) ^ (row & 7);
    aSrc[it] = Ab8  + (size_t)(r0 + row) * K2 + kc * 16;
    bSrc[it] = wbt8 + (size_t)(c0 + row) * K2 + kc * 16;
    dstOff[it] = p16 * 16;
  }

  f32x4 zero; zero[0] = 0.f; zero[1] = 0.f; zero[2] = 0.f; zero[3] = 0.f;
  f32x4 acc[4][4];
  #pragma unroll
  for (int a = 0; a < 4; ++a)
    #pragma unroll
    for (int b = 0; b < 4; ++b) acc[a][b] = zero;

  for (int kb = 0; kb < K2; kb += BK8) {   // 64 iterations
    __syncthreads();
    #pragma unroll
    for (int it = 0; it < 4; ++it) {
      gl2lds16(aSrc[it] + kb, &As[dstOff[it]]);
      gl2lds16(bSrc[it] + kb, &Bs[dstOff[it]]);
    }
    __syncthreads();
    union frag { int32x8 v; uint4 q[2]; };
    frag af[4], bfv[4];
    #pragma unroll
    for (int t4 = 0; t4 < 4; ++t4) {
      af[t4].q[0]  = *(const uint4*)&As[a_off[t4][0]];
      af[t4].q[1]  = *(const uint4*)&As[a_off[t4][1]];
      bfv[t4].q[0] = *(const uint4*)&Bs[b_off[t4][0]];
      bfv[t4].q[1] = *(const uint4*)&Bs[b_off[t4][1]];
    }
    #pragma unroll
    for (int tm = 0; tm < 4; ++tm)
      #pragma unroll
      for (int tn = 0; tn < 4; ++tn)
        acc[tm][tn] = __builtin_amdgcn_mfma_scale_f32_16x16x128_f8f6f4(
            af[tm].v, bfv[tn].v, acc[tm][tn],
            0 /*cbsz: A=FP8*/, 0 /*blgp: B=FP8*/,
            0, 0x7F7F7F7F /*A scales = 1.0 (e8m0=127)*/,
            0, 0x7F7F7F7F /*B scales = 1.0*/);
  }

  #pragma unroll
  for (int tm = 0; tm < 4; ++tm) {
    const int row = r0 + wm * 64 + tm * 16 + quad * 4;
    #pragma unroll
    for (int tn = 0; tn < 4; ++tn) {
      const int col = c0 + wn * 64 + tn * 16 + l15;
      float* op = out + (size_t)row * OUT_F + col;
      #pragma unroll
      for (int r = 0; r < 4; ++r)
        op[(size_t)r * OUT_F] += acc[tm][tn][r];
    }
  }
}

// ---------- fallback path (ws too small): full-W bf16 prep + fused gemm ----------
__global__ __launch_bounds__(256)
void kan_prep_w_full(const float* __restrict__ sb, const float* __restrict__ sw,
                     const float* __restrict__ ss, __bf16* __restrict__ wbt) {
  const int t = threadIdx.x;
  if (blockIdx.x < 256) {
    __shared__ float tile[64][65];
    const int o0 = (blockIdx.x & 15) * 64, k0 = (blockIdx.x >> 4) * 64;
    const int r = t >> 4, c4 = (t & 15) * 4;
    #pragma unroll
    for (int it = 0; it < 4; ++it) {
      const int k = k0 + r + it * 16;
      float4 v = *(const float4*)(sb + (size_t)k * OUT_F + o0 + c4);
      tile[r + it * 16][c4 + 0] = v.x; tile[r + it * 16][c4 + 1] = v.y;
      tile[r + it * 16][c4 + 2] = v.z; tile[r + it * 16][c4 + 3] = v.w;
    }
    __syncthreads();
    #pragma unroll
    for (int it = 0; it < 4; ++it) {
      const int ol = r + it * 16;
      union { __bf16 h[4]; uint2 q; } s;
      #pragma unroll
      for (int e = 0; e < 4; ++e) s.h[e] = (__bf16)tile[c4 + e][ol];
      *(uint2*)(wbt + (size_t)(o0 + ol) * KTOT + k0 + c4) = s.q;
    }
  } else {
    const size_t e = ((size_t)(blockIdx.x - 256) * 256 + t) * 8;
    const int o = (int)(e >> 13);
    const int j = (int)(e & 8191);
    const int i = j >> 3;
    const float sc = ss[(size_t)i * OUT_F + o];
    float4 a = *(const float4*)(sw + e);
    float4 b = *(const float4*)(sw + e + 4);
    float vv[8] = {a.x, a.y, a.z, a.w, b.x, b.y, b.z, b.w};
    union { __bf16 h[8]; uint4 q; } s;
    #pragma unroll
    for (int g = 0; g < 8; ++g) s.h[g] = (__bf16)(vv[g] * sc);
    *(uint4*)(wbt + (size_t)o * KTOT + IN_F + j) = s.q;
  }
}

__global__ __launch_bounds__(256, 2)
void kan_gemm_fused(const float* __restrict__ x, const __bf16* __restrict__ wbt,
                    const float* __restrict__ grid, const float* __restrict__ sigma,
                    float* __restrict__ out) {
  __shared__ __bf16 As[BM * BK];
  __shared__ __bf16 Bs[BN * BK];
  __shared__ float  gLds[IN_F * GRID_N];
  const int tid = threadIdx.x;
  const int bx  = blockIdx.x;
  const int c0  = (bx & 7) * BN;
  const int r0  = (bx >> 3) * BM;
  for (int idx = tid; idx < IN_F * GRID_N / 4; idx += 256)
    ((float4*)gLds)[idx] = ((const float4*)grid)[idx];
  const float inv_sigma = 1.0f / sigma[0];
  const int lane = tid & 63, wave = tid >> 6;
  const int wm = wave & 1, wn = wave >> 1;
  const int quad = lane >> 4, l15 = lane & 15;
  f32x4 zero; zero[0] = 0.f; zero[1] = 0.f; zero[2] = 0.f; zero[3] = 0.f;
  f32x4 acc[4][4];
  #pragma unroll
  for (int a = 0; a < 4; ++a)
    #pragma unroll
    for (int b = 0; b < 4; ++b) acc[a][b] = zero;
  const int m = tid >> 1, half = tid & 1;
  const float* xrow = x + (size_t)(r0 + m) * IN_F;
  __syncthreads();
  for (int kb = 0; kb < KTOT; kb += BK) {
    union { __bf16 h[32]; uint4 q[4]; } av;
    if (kb < IN_F) {
      const float4* xp = (const float4*)(xrow + kb + half * 32);
      #pragma unroll
      for (int j4 = 0; j4 < 8; ++j4) {
        float4 v = xp[j4];
        float vv[4] = {v.x, v.y, v.z, v.w};
        #pragma unroll
        for (int e = 0; e < 4; ++e)
          av.h[j4 * 4 + e] = (__bf16)(vv[e] / (1.0f + __expf(-vv[e])));
      }
    } else {
      const int i0 = (kb - IN_F) >> 3;
      float4 xv = *(const float4*)(xrow + i0 + half * 4);
      float xs[4] = {xv.x, xv.y, xv.z, xv.w};
      #pragma unroll
      for (int ii = 0; ii < 4; ++ii) {
        const float u = xs[ii];
        const float* gp = &gLds[(i0 + half * 4 + ii) * GRID_N];
        #pragma unroll
        for (int g = 0; g < GRID_N; ++g) {
          float d = (u - gp[g]) * inv_sigma;
          av.h[ii * 8 + g] = (__bf16)__expf(-d * d);
        }
      }
    }
    __syncthreads();
    {
      uint4* dst = (uint4*)&As[m * BK + half * 32];
      #pragma unroll
      for (int qd = 0; qd < 4; ++qd) dst[qd] = av.q[qd];
    }
    #pragma unroll
    for (int it = 0; it < 4; ++it) {
      const int idx = it * 2048 + tid * 8;
      const int n = idx >> 6, k = idx & 63;
      gl2lds16(wbt + (size_t)(c0 + n) * KTOT + kb + k, &Bs[idx]);
    }
    __syncthreads();
    #pragma unroll
    for (int ks = 0; ks < 2; ++ks) {
      bf16x8 af[4], bfv[4];
      #pragma unroll
      for (int t4 = 0; t4 < 4; ++t4)
        af[t4] = *(const bf16x8*)&As[(wm * 64 + t4 * 16 + l15) * BK + ks * 32 + quad * 8];
      #pragma unroll
      for (int t4 = 0; t4 < 4; ++t4)
        bfv[t4] = *(const bf16x8*)&Bs[(wn * 64 + t4 * 16 + l15) * BK + ks * 32 + quad * 8];
      #pragma unroll
      for (int tm = 0; tm < 4; ++tm)
        #pragma unroll
        for (int tn = 0; tn < 4; ++tn)
          acc[tm][tn] = __builtin_amdgcn_mfma_f32_16x16x32_bf16(
              af[tm], bfv[tn], acc[tm][tn], 0, 0, 0);
    }
  }
  #pragma unroll
  for (int tm = 0; tm < 4; ++tm) {
    const int row = r0 + wm * 64 + tm * 16 + quad * 4;
    #pragma unroll
    for (int tn = 0; tn < 4; ++tn) {
      const int col = c0 + wn * 64 + tn * 16 + l15;
      float* op = out + (size_t)row * OUT_F + col;
      #pragma unroll
      for (int r = 0; r < 4; ++r)
        op[(size_t)r * OUT_F] = acc[tm][tn][r];
    }
  }
}

extern "C" void kernel_launch(void* const* d_in, const int* in_sizes, int n_in,
                              void* d_out, int out_size, void* d_ws, size_t ws_size,
                              hipStream_t stream) {
  const float* x     = (const float*)d_in[0];
  const float* sb    = (const float*)d_in[1];
  const float* sw    = (const float*)d_in[2];
  const float* ss    = (const float*)d_in[3];
  const float* grid  = (const float*)d_in[4];
  const float* sigma = (const float*)d_in[5];
  float* out = (float*)d_out;

  const size_t SBT_BYTES = (size_t)OUT_F * IN_F * 2;   //   2 MB (bf16)
  const size_t WS_BYTES  = (size_t)OUT_F * K2;         //  8.4 MB (fp8)
  const size_t A_BYTES   = (size_t)BATCH * K2;         // 67.1 MB (fp8)
  // total needed: ~77.5 MB

  if (ws_size >= SBT_BYTES + WS_BYTES + A_BYTES) {
    __bf16*        sbT  = (__bf16*)d_ws;
    unsigned char* wbt8 = (unsigned char*)d_ws + SBT_BYTES;
    unsigned char* Ab8  = (unsigned char*)d_ws + SBT_BYTES + WS_BYTES;
    kan_transpose_sb<<<dim3(256), dim3(256), 0, stream>>>(sb, sbT);
    kan_mix<<<dim3(512 + 4096 + BATCH), dim3(256), 0, stream>>>(
        x, sbT, sw, ss, grid, sigma, wbt8, Ab8, out);
    kan_gemm_spline_fp8<<<dim3((BATCH / BM) * (OUT_F / BN)), dim3(256), 0, stream>>>(
        Ab8, wbt8, out);
  } else {
    __bf16* wbt = (__bf16*)d_ws;   // 18.9 MB
    kan_prep_w_full<<<dim3(4352), dim3(256), 0, stream>>>(sb, sw, ss, wbt);
    kan_gemm_fused<<<dim3((BATCH / BM) * (OUT_F / BN)), dim3(256), 0, stream>>>(
        x, wbt, grid, sigma, out);
  }
}

// Round 8
// 223.471 us; speedup vs baseline: 1.6587x; 1.1871x over previous
//
#include <hip/hip_runtime.h>

// KanLinear: out[b,o] = silu(x)@scale_base + bases@(spline_w*scale_spline)
// Round 8:
//  - ONE gemm kernel, two K-phases sharing the accumulator: 64 fp8
//    mfma_scale_16x16x128 iters (spline, K=8192) + 16 bf16 mfma_16x16x32
//    iters (base, K=1024). C/D layout is shape-determined (m121-128) so the
//    phases accumulate together; epilogue is a plain store (kills r7's 32MB
//    out read-modify-write).
//  - kan_mix is now PURE elementwise (no MFMA, per-row x fusion reads x once;
//    sb-transpose folded in). r7: mix ran 172MB at 1.5TB/s (4x off floor)
//    because 512 heavy gemm blocks time-shared CUs with 12288 light ones.
//  - Kept: 128x128 tiles, XOR-swizzled LDS (conflicts=0), XCD swizzle.

#define BATCH 8192
#define IN_F  1024
#define OUT_F 1024
#define GRID_N 8
#define K2    (IN_F * GRID_N)          // spline K = 8192
#define KTOT  (IN_F + K2)              // 9216 (fallback path)

#define BM 128
#define BN 128
#define BK 64        // bf16 k-tile
#define BK8 128      // fp8 k-tile (bytes)

typedef __bf16 bf16x8 __attribute__((ext_vector_type(8)));
typedef float  f32x4  __attribute__((ext_vector_type(4)));
typedef int    int32x8 __attribute__((ext_vector_type(8)));

__device__ __forceinline__ void gl2lds16(const void* g, void* l) {
  __builtin_amdgcn_global_load_lds(
      (const __attribute__((address_space(1))) void*)g,
      (__attribute__((address_space(3))) void*)l, 16, 0, 0);
}

__device__ __forceinline__ void pack_fp8x8(const float* v, int& w0, int& w1) {
  w0 = 0; w1 = 0;
  w0 = __builtin_amdgcn_cvt_pk_fp8_f32(v[0], v[1], w0, false);
  w0 = __builtin_amdgcn_cvt_pk_fp8_f32(v[2], v[3], w0, true);
  w1 = __builtin_amdgcn_cvt_pk_fp8_f32(v[4], v[5], w1, false);
  w1 = __builtin_amdgcn_cvt_pk_fp8_f32(v[6], v[7], w1, true);
}

// ---------- launch 1: pure elementwise prep ----------
// blocks [0,256):       sbT[o][k] = (bf16)scale_base[k][o]  (LDS transpose)
// blocks [256,4352):    wbt8[o][j] = fp8(sw[o*8192+j] * ss[(j>>3)*1024+o])
// blocks [4352,12544):  row b: sbA[b][k]=bf16(silu(x)), Ab8[b][i*8+g]=fp8(base)
__global__ __launch_bounds__(256)
void kan_mix(const float* __restrict__ x, const float* __restrict__ sb,
             const float* __restrict__ sw, const float* __restrict__ ss,
             const float* __restrict__ grid, const float* __restrict__ sigma,
             __bf16* __restrict__ sbT, unsigned char* __restrict__ wbt8,
             unsigned char* __restrict__ Ab8, __bf16* __restrict__ sbA) {
  const int t = threadIdx.x;
  const int bx = blockIdx.x;
  if (bx < 256) {
    __shared__ float tile[64][65];
    const int o0 = (bx & 15) * 64, k0 = (bx >> 4) * 64;
    const int r = t >> 4, c4 = (t & 15) * 4;
    #pragma unroll
    for (int it = 0; it < 4; ++it) {
      const int k = k0 + r + it * 16;
      float4 v = *(const float4*)(sb + (size_t)k * OUT_F + o0 + c4);
      tile[r + it * 16][c4 + 0] = v.x; tile[r + it * 16][c4 + 1] = v.y;
      tile[r + it * 16][c4 + 2] = v.z; tile[r + it * 16][c4 + 3] = v.w;
    }
    __syncthreads();
    #pragma unroll
    for (int it = 0; it < 4; ++it) {
      const int ol = r + it * 16;
      union { __bf16 h[4]; uint2 q; } s;
      #pragma unroll
      for (int e = 0; e < 4; ++e) s.h[e] = (__bf16)tile[c4 + e][ol];
      *(uint2*)(sbT + (size_t)(o0 + ol) * IN_F + k0 + c4) = s.q;
    }
  } else if (bx < 4352) {
    const size_t e = ((size_t)(bx - 256) * 256 + t) * 8;
    const int o = (int)(e >> 13);
    const int j = (int)(e & 8191);
    const int i = j >> 3;
    const float sc = ss[(size_t)i * OUT_F + o];
    float4 a = *(const float4*)(sw + e);
    float4 b = *(const float4*)(sw + e + 4);
    float vv[8] = {a.x * sc, a.y * sc, a.z * sc, a.w * sc,
                   b.x * sc, b.y * sc, b.z * sc, b.w * sc};
    int w0, w1; pack_fp8x8(vv, w0, w1);
    *(int2*)(wbt8 + (size_t)o * K2 + j) = make_int2(w0, w1);
  } else {
    const int b = bx - 4352;
    const float inv_sigma = 1.0f / sigma[0];
    const float* xrow = x + (size_t)b * IN_F;
    unsigned char* arow = Ab8 + (size_t)b * K2;
    __bf16* srow = sbA + (size_t)b * IN_F;
    // read x once per row: thread t owns elems 4t..4t+3 for silu,
    // and i = t+it*256 for bases (re-read from L1/L2, cheap).
    {
      float4 v = ((const float4*)xrow)[t];
      float vv[4] = {v.x, v.y, v.z, v.w};
      union { __bf16 h[4]; uint2 q; } s;
      #pragma unroll
      for (int e = 0; e < 4; ++e) s.h[e] = (__bf16)(vv[e] / (1.0f + __expf(-vv[e])));
      ((uint2*)srow)[t] = s.q;
    }
    #pragma unroll
    for (int it = 0; it < 4; ++it) {
      const int i = t + it * 256;
      const float u = xrow[i];
      float4 g0 = *(const float4*)(grid + (size_t)i * GRID_N);
      float4 g1 = *(const float4*)(grid + (size_t)i * GRID_N + 4);
      float gg[8] = {g0.x, g0.y, g0.z, g0.w, g1.x, g1.y, g1.z, g1.w};
      float bb[8];
      #pragma unroll
      for (int g = 0; g < GRID_N; ++g) {
        float d = (u - gg[g]) * inv_sigma;
        bb[g] = __expf(-d * d);
      }
      int w0, w1; pack_fp8x8(bb, w0, w1);
      *(int2*)(arow + (size_t)i * GRID_N) = make_int2(w0, w1);
    }
  }
}

// ---------- launch 2: unified GEMM, fp8 phase (K=8192) + bf16 phase (K=1024) ----------
__global__ __launch_bounds__(256)
void kan_gemm_all(const unsigned char* __restrict__ Ab8,
                  const unsigned char* __restrict__ wbt8,
                  const __bf16* __restrict__ sbA,
                  const __bf16* __restrict__ sbT,
                  float* __restrict__ out) {
  __shared__ unsigned char As8[BM * BK8];   // 16 KB; bf16 phase aliases it
  __shared__ unsigned char Bs8[BN * BK8];   // 16 KB
  __bf16* As16 = (__bf16*)As8;
  __bf16* Bs16 = (__bf16*)Bs8;

  const int tid = threadIdx.x;
  const int bx  = blockIdx.x;
  const int s   = bx >> 3;
  const int r0  = ((bx & 7) * 8 + (s >> 3)) * BM;
  const int c0  = (s & 7) * BN;

  const int lane = tid & 63, wave = tid >> 6;
  const int wm = wave & 1, wn = wave >> 1;
  const int quad = lane >> 4, l15 = lane & 15;

  // --- hoisted fp8-phase LDS byte offsets (lane reads 32B: chunks quad*2,+1)
  int a_off8[4][2], b_off8[4][2];
  #pragma unroll
  for (int t4 = 0; t4 < 4; ++t4) {
    const int rowA = wm * 64 + t4 * 16 + l15;
    const int rowB = wn * 64 + t4 * 16 + l15;
    #pragma unroll
    for (int h = 0; h < 2; ++h) {
      a_off8[t4][h] = rowA * BK8 + (((quad * 2 + h) ^ (rowA & 7)) * 16);
      b_off8[t4][h] = rowB * BK8 + (((quad * 2 + h) ^ (rowB & 7)) * 16);
    }
  }
  // --- hoisted bf16-phase LDS element offsets
  int a_off16[2][4], b_off16[2][4];
  #pragma unroll
  for (int ks = 0; ks < 2; ++ks) {
    const int kc = ks * 4 + quad;
    #pragma unroll
    for (int t4 = 0; t4 < 4; ++t4) {
      const int rowA = wm * 64 + t4 * 16 + l15;
      a_off16[ks][t4] = (rowA * 8 + (kc ^ (rowA & 7))) * 8;
      const int rowB = wn * 64 + t4 * 16 + l15;
      b_off16[ks][t4] = (rowB * 8 + (kc ^ (rowB & 7))) * 8;
    }
  }
  // --- hoisted staging descriptors (both phases: 1024 16B-chunks = 4 iters)
  const int p16 = tid;     // pattern repeated with +256*it
  const unsigned char* aSrc8[4]; const unsigned char* bSrc8[4];
  const __bf16* aSrc16[4]; const __bf16* bSrc16[4]; int dstOff[4];
  #pragma unroll
  for (int it = 0; it < 4; ++it) {
    const int p = it * 256 + p16;
    const int row = p >> 3;
    const int kc  = (p & 7) ^ (row & 7);
    aSrc8[it]  = Ab8  + (size_t)(r0 + row) * K2 + kc * 16;
    bSrc8[it]  = wbt8 + (size_t)(c0 + row) * K2 + kc * 16;
    aSrc16[it] = sbA  + (size_t)(r0 + row) * IN_F + kc * 8;
    bSrc16[it] = sbT  + (size_t)(c0 + row) * IN_F + kc * 8;
    dstOff[it] = p * 16;   // bytes (fp8); bf16 phase uses p*8 elems = same bytes
  }

  f32x4 zero; zero[0] = 0.f; zero[1] = 0.f; zero[2] = 0.f; zero[3] = 0.f;
  f32x4 acc[4][4];
  #pragma unroll
  for (int a = 0; a < 4; ++a)
    #pragma unroll
    for (int b = 0; b < 4; ++b) acc[a][b] = zero;

  // ---- phase 1: fp8 spline, 64 iters ----
  for (int kb = 0; kb < K2; kb += BK8) {
    __syncthreads();
    #pragma unroll
    for (int it = 0; it < 4; ++it) {
      gl2lds16(aSrc8[it] + kb, &As8[dstOff[it]]);
      gl2lds16(bSrc8[it] + kb, &Bs8[dstOff[it]]);
    }
    __syncthreads();
    union frag { int32x8 v; uint4 q[2]; };
    frag af[4], bfv[4];
    #pragma unroll
    for (int t4 = 0; t4 < 4; ++t4) {
      af[t4].q[0]  = *(const uint4*)&As8[a_off8[t4][0]];
      af[t4].q[1]  = *(const uint4*)&As8[a_off8[t4][1]];
      bfv[t4].q[0] = *(const uint4*)&Bs8[b_off8[t4][0]];
      bfv[t4].q[1] = *(const uint4*)&Bs8[b_off8[t4][1]];
    }
    #pragma unroll
    for (int tm = 0; tm < 4; ++tm)
      #pragma unroll
      for (int tn = 0; tn < 4; ++tn)
        acc[tm][tn] = __builtin_amdgcn_mfma_scale_f32_16x16x128_f8f6f4(
            af[tm].v, bfv[tn].v, acc[tm][tn],
            0, 0, 0, 0x7F7F7F7F, 0, 0x7F7F7F7F);
  }

  // ---- phase 2: bf16 base, 16 iters (same acc, same C layout) ----
  for (int kb = 0; kb < IN_F; kb += BK) {
    __syncthreads();
    #pragma unroll
    for (int it = 0; it < 4; ++it) {
      gl2lds16(aSrc16[it] + kb, (char*)As16 + dstOff[it]);
      gl2lds16(bSrc16[it] + kb, (char*)Bs16 + dstOff[it]);
    }
    __syncthreads();
    #pragma unroll
    for (int ks = 0; ks < 2; ++ks) {
      bf16x8 af[4], bfv[4];
      #pragma unroll
      for (int t4 = 0; t4 < 4; ++t4) af[t4]  = *(const bf16x8*)&As16[a_off16[ks][t4]];
      #pragma unroll
      for (int t4 = 0; t4 < 4; ++t4) bfv[t4] = *(const bf16x8*)&Bs16[b_off16[ks][t4]];
      #pragma unroll
      for (int tm = 0; tm < 4; ++tm)
        #pragma unroll
        for (int tn = 0; tn < 4; ++tn)
          acc[tm][tn] = __builtin_amdgcn_mfma_f32_16x16x32_bf16(
              af[tm], bfv[tn], acc[tm][tn], 0, 0, 0);
    }
  }

  // ---- epilogue: plain store ----
  #pragma unroll
  for (int tm = 0; tm < 4; ++tm) {
    const int row = r0 + wm * 64 + tm * 16 + quad * 4;
    #pragma unroll
    for (int tn = 0; tn < 4; ++tn) {
      const int col = c0 + wn * 64 + tn * 16 + l15;
      float* op = out + (size_t)row * OUT_F + col;
      #pragma unroll
      for (int r = 0; r < 4; ++r)
        op[(size_t)r * OUT_F] = acc[tm][tn][r];
    }
  }
}

// ---------- fallback path (ws too small): full-W bf16 prep + fused gemm ----------
__global__ __launch_bounds__(256)
void kan_prep_w_full(const float* __restrict__ sb, const float* __restrict__ sw,
                     const float* __restrict__ ss, __bf16* __restrict__ wbt) {
  const int t = threadIdx.x;
  if (blockIdx.x < 256) {
    __shared__ float tile[64][65];
    const int o0 = (blockIdx.x & 15) * 64, k0 = (blockIdx.x >> 4) * 64;
    const int r = t >> 4, c4 = (t & 15) * 4;
    #pragma unroll
    for (int it = 0; it < 4; ++it) {
      const int k = k0 + r + it * 16;
      float4 v = *(const float4*)(sb + (size_t)k * OUT_F + o0 + c4);
      tile[r + it * 16][c4 + 0] = v.x; tile[r + it * 16][c4 + 1] = v.y;
      tile[r + it * 16][c4 + 2] = v.z; tile[r + it * 16][c4 + 3] = v.w;
    }
    __syncthreads();
    #pragma unroll
    for (int it = 0; it < 4; ++it) {
      const int ol = r + it * 16;
      union { __bf16 h[4]; uint2 q; } s;
      #pragma unroll
      for (int e = 0; e < 4; ++e) s.h[e] = (__bf16)tile[c4 + e][ol];
      *(uint2*)(wbt + (size_t)(o0 + ol) * KTOT + k0 + c4) = s.q;
    }
  } else {
    const size_t e = ((size_t)(blockIdx.x - 256) * 256 + t) * 8;
    const int o = (int)(e >> 13);
    const int j = (int)(e & 8191);
    const int i = j >> 3;
    const float sc = ss[(size_t)i * OUT_F + o];
    float4 a = *(const float4*)(sw + e);
    float4 b = *(const float4*)(sw + e + 4);
    float vv[8] = {a.x, a.y, a.z, a.w, b.x, b.y, b.z, b.w};
    union { __bf16 h[8]; uint4 q; } s;
    #pragma unroll
    for (int g = 0; g < 8; ++g) s.h[g] = (__bf16)(vv[g] * sc);
    *(uint4*)(wbt + (size_t)o * KTOT + IN_F + j) = s.q;
  }
}

__global__ __launch_bounds__(256, 2)
void kan_gemm_fused(const float* __restrict__ x, const __bf16* __restrict__ wbt,
                    const float* __restrict__ grid, const float* __restrict__ sigma,
                    float* __restrict__ out) {
  __shared__ __bf16 As[BM * BK];
  __shared__ __bf16 Bs[BN * BK];
  __shared__ float  gLds[IN_F * GRID_N];
  const int tid = threadIdx.x;
  const int bx  = blockIdx.x;
  const int c0  = (bx & 7) * BN;
  const int r0  = (bx >> 3) * BM;
  for (int idx = tid; idx < IN_F * GRID_N / 4; idx += 256)
    ((float4*)gLds)[idx] = ((const float4*)grid)[idx];
  const float inv_sigma = 1.0f / sigma[0];
  const int lane = tid & 63, wave = tid >> 6;
  const int wm = wave & 1, wn = wave >> 1;
  const int quad = lane >> 4, l15 = lane & 15;
  f32x4 zero; zero[0] = 0.f; zero[1] = 0.f; zero[2] = 0.f; zero[3] = 0.f;
  f32x4 acc[4][4];
  #pragma unroll
  for (int a = 0; a < 4; ++a)
    #pragma unroll
    for (int b = 0; b < 4; ++b) acc[a][b] = zero;
  const int m = tid >> 1, half = tid & 1;
  const float* xrow = x + (size_t)(r0 + m) * IN_F;
  __syncthreads();
  for (int kb = 0; kb < KTOT; kb += BK) {
    union { __bf16 h[32]; uint4 q[4]; } av;
    if (kb < IN_F) {
      const float4* xp = (const float4*)(xrow + kb + half * 32);
      #pragma unroll
      for (int j4 = 0; j4 < 8; ++j4) {
        float4 v = xp[j4];
        float vv[4] = {v.x, v.y, v.z, v.w};
        #pragma unroll
        for (int e = 0; e < 4; ++e)
          av.h[j4 * 4 + e] = (__bf16)(vv[e] / (1.0f + __expf(-vv[e])));
      }
    } else {
      const int i0 = (kb - IN_F) >> 3;
      float4 xv = *(const float4*)(xrow + i0 + half * 4);
      float xs[4] = {xv.x, xv.y, xv.z, xv.w};
      #pragma unroll
      for (int ii = 0; ii < 4; ++ii) {
        const float u = xs[ii];
        const float* gp = &gLds[(i0 + half * 4 + ii) * GRID_N];
        #pragma unroll
        for (int g = 0; g < GRID_N; ++g) {
          float d = (u - gp[g]) * inv_sigma;
          av.h[ii * 8 + g] = (__bf16)__expf(-d * d);
        }
      }
    }
    __syncthreads();
    {
      uint4* dst = (uint4*)&As[m * BK + half * 32];
      #pragma unroll
      for (int qd = 0; qd < 4; ++qd) dst[qd] = av.q[qd];
    }
    #pragma unroll
    for (int it = 0; it < 4; ++it) {
      const int idx = it * 2048 + tid * 8;
      const int n = idx >> 6, k = idx & 63;
      gl2lds16(wbt + (size_t)(c0 + n) * KTOT + kb + k, &Bs[idx]);
    }
    __syncthreads();
    #pragma unroll
    for (int ks = 0; ks < 2; ++ks) {
      bf16x8 af[4], bfv[4];
      #pragma unroll
      for (int t4 = 0; t4 < 4; ++t4)
        af[t4] = *(const bf16x8*)&As[(wm * 64 + t4 * 16 + l15) * BK + ks * 32 + quad * 8];
      #pragma unroll
      for (int t4 = 0; t4 < 4; ++t4)
        bfv[t4] = *(const bf16x8*)&Bs[(wn * 64 + t4 * 16 + l15) * BK + ks * 32 + quad * 8];
      #pragma unroll
      for (int tm = 0; tm < 4; ++tm)
        #pragma unroll
        for (int tn = 0; tn < 4; ++tn)
          acc[tm][tn] = __builtin_amdgcn_mfma_f32_16x16x32_bf16(
              af[tm], bfv[tn], acc[tm][tn], 0, 0, 0);
    }
  }
  #pragma unroll
  for (int tm = 0; tm < 4; ++tm) {
    const int row = r0 + wm * 64 + tm * 16 + quad * 4;
    #pragma unroll
    for (int tn = 0; tn < 4; ++tn) {
      const int col = c0 + wn * 64 + tn * 16 + l15;
      float* op = out + (size_t)row * OUT_F + col;
      #pragma unroll
      for (int r = 0; r < 4; ++r)
        op[(size_t)r * OUT_F] = acc[tm][tn][r];
    }
  }
}

extern "C" void kernel_launch(void* const* d_in, const int* in_sizes, int n_in,
                              void* d_out, int out_size, void* d_ws, size_t ws_size,
                              hipStream_t stream) {
  const float* x     = (const float*)d_in[0];
  const float* sb    = (const float*)d_in[1];
  const float* sw    = (const float*)d_in[2];
  const float* ss    = (const float*)d_in[3];
  const float* grid  = (const float*)d_in[4];
  const float* sigma = (const float*)d_in[5];
  float* out = (float*)d_out;

  const size_t SBT_BYTES = (size_t)OUT_F * IN_F * 2;   //   2 MB (bf16)
  const size_t WS_BYTES  = (size_t)OUT_F * K2;         //  8.4 MB (fp8)
  const size_t A_BYTES   = (size_t)BATCH * K2;         // 67.1 MB (fp8)
  const size_t SBA_BYTES = (size_t)BATCH * IN_F * 2;   // 16.8 MB (bf16)
  // total needed: ~94.3 MB

  if (ws_size >= SBT_BYTES + WS_BYTES + A_BYTES + SBA_BYTES) {
    __bf16*        sbT  = (__bf16*)d_ws;
    unsigned char* wbt8 = (unsigned char*)d_ws + SBT_BYTES;
    unsigned char* Ab8  = (unsigned char*)d_ws + SBT_BYTES + WS_BYTES;
    __bf16*        sbA  = (__bf16*)((char*)d_ws + SBT_BYTES + WS_BYTES + A_BYTES);
    kan_mix<<<dim3(4352 + BATCH), dim3(256), 0, stream>>>(
        x, sb, sw, ss, grid, sigma, sbT, wbt8, Ab8, sbA);
    kan_gemm_all<<<dim3((BATCH / BM) * (OUT_F / BN)), dim3(256), 0, stream>>>(
        Ab8, wbt8, sbA, sbT, out);
  } else {
    __bf16* wbt = (__bf16*)d_ws;   // 18.9 MB
    kan_prep_w_full<<<dim3(4352), dim3(256), 0, stream>>>(sb, sw, ss, wbt);
    kan_gemm_fused<<<dim3((BATCH / BM) * (OUT_F / BN)), dim3(256), 0, stream>>>(
        x, wbt, grid, sigma, out);
  }
}

// Round 9
// 219.392 us; speedup vs baseline: 1.6895x; 1.0186x over previous
//
#include <hip/hip_runtime.h>

// KanLinear: out[b,o] = silu(x)@scale_base + bases@(spline_w*scale_spline)
// Round 9:
//  - kan_mix spline-pack restructured into 64ox512j tile-blocks: ss staged
//    via the proven 64x64 LDS transpose (r8 read ss with 4KB lane stride =
//    64 cache lines/wave -> mix ran at 1.5TB/s, 2.4x off its memory floor).
//    Now every global stream in mix is coalesced.
//  - Gemm untouched: unified 2-phase (fp8 MX K=8192 + bf16 K=1024, shared
//    accumulator) at 99us = the m148 structure plateau (~1555 TF effective).
//  - Kept: 128x128 tiles, XOR-swizzled LDS, XCD swizzle, plain-store epilogue.

#define BATCH 8192
#define IN_F  1024
#define OUT_F 1024
#define GRID_N 8
#define K2    (IN_F * GRID_N)          // spline K = 8192
#define KTOT  (IN_F + K2)              // 9216 (fallback path)

#define BM 128
#define BN 128
#define BK 64        // bf16 k-tile
#define BK8 128      // fp8 k-tile (bytes)

typedef __bf16 bf16x8 __attribute__((ext_vector_type(8)));
typedef float  f32x4  __attribute__((ext_vector_type(4)));
typedef int    int32x8 __attribute__((ext_vector_type(8)));

__device__ __forceinline__ void gl2lds16(const void* g, void* l) {
  __builtin_amdgcn_global_load_lds(
      (const __attribute__((address_space(1))) void*)g,
      (__attribute__((address_space(3))) void*)l, 16, 0, 0);
}

__device__ __forceinline__ void pack_fp8x8(const float* v, int& w0, int& w1) {
  w0 = 0; w1 = 0;
  w0 = __builtin_amdgcn_cvt_pk_fp8_f32(v[0], v[1], w0, false);
  w0 = __builtin_amdgcn_cvt_pk_fp8_f32(v[2], v[3], w0, true);
  w1 = __builtin_amdgcn_cvt_pk_fp8_f32(v[4], v[5], w1, false);
  w1 = __builtin_amdgcn_cvt_pk_fp8_f32(v[6], v[7], w1, true);
}

// ---------- launch 1: pure elementwise prep, all streams coalesced ----------
// blocks [0,256):      sbT[o][k] = (bf16)scale_base[k][o]  (LDS transpose)
// blocks [256,512):    spline-pack tile 64o x 512j with LDS-staged ss
// blocks [512,8704):   row b: sbA[b][k]=bf16(silu(x)), Ab8[b][i*8+g]=fp8(base)
__global__ __launch_bounds__(256)
void kan_mix(const float* __restrict__ x, const float* __restrict__ sb,
             const float* __restrict__ sw, const float* __restrict__ ss,
             const float* __restrict__ grid, const float* __restrict__ sigma,
             __bf16* __restrict__ sbT, unsigned char* __restrict__ wbt8,
             unsigned char* __restrict__ Ab8, __bf16* __restrict__ sbA) {
  const int t = threadIdx.x;
  const int bx = blockIdx.x;
  if (bx < 256) {
    // ---- sb transpose (64x64 f32 tiles) ----
    __shared__ float tile[64][65];
    const int o0 = (bx & 15) * 64, k0 = (bx >> 4) * 64;
    const int r = t >> 4, c4 = (t & 15) * 4;
    #pragma unroll
    for (int it = 0; it < 4; ++it) {
      const int k = k0 + r + it * 16;
      float4 v = *(const float4*)(sb + (size_t)k * OUT_F + o0 + c4);
      tile[r + it * 16][c4 + 0] = v.x; tile[r + it * 16][c4 + 1] = v.y;
      tile[r + it * 16][c4 + 2] = v.z; tile[r + it * 16][c4 + 3] = v.w;
    }
    __syncthreads();
    #pragma unroll
    for (int it = 0; it < 4; ++it) {
      const int ol = r + it * 16;
      union { __bf16 h[4]; uint2 q; } s;
      #pragma unroll
      for (int e = 0; e < 4; ++e) s.h[e] = (__bf16)tile[c4 + e][ol];
      *(uint2*)(sbT + (size_t)(o0 + ol) * IN_F + k0 + c4) = s.q;
    }
  } else if (bx < 512) {
    // ---- spline-pack: tile = o in [o0,o0+64), j in [j0,j0+512), i=j/8 ----
    __shared__ float tile[64][65];        // tile[i_local][o_local]
    const int sp = bx - 256;              // [0,256)
    const int o0 = (sp >> 4) * 64;
    const int j0 = (sp & 15) * 512;
    const int i0 = j0 >> 3;               // 64 i's per tile
    // stage ss[i0..i0+64)[o0..o0+64) coalesced (float4 per lane)
    const int r = t >> 4, c4 = (t & 15) * 4;
    #pragma unroll
    for (int it = 0; it < 4; ++it) {
      const int i = i0 + r + it * 16;
      float4 v = *(const float4*)(ss + (size_t)i * OUT_F + o0 + c4);
      tile[r + it * 16][c4 + 0] = v.x; tile[r + it * 16][c4 + 1] = v.y;
      tile[r + it * 16][c4 + 2] = v.z; tile[r + it * 16][c4 + 3] = v.w;
    }
    __syncthreads();
    // pack: pass p handles flat f = p*256+t over 4096 (o_l,i_l) pairs,
    // i_l fastest -> sw reads & wbt8 writes fully coalesced.
    #pragma unroll
    for (int p = 0; p < 16; ++p) {
      const int f = p * 256 + t;
      const int o_l = f >> 6, i_l = f & 63;
      const float sc = tile[i_l][o_l];
      const float* swp = sw + (size_t)(o0 + o_l) * K2 + j0 + i_l * 8;
      float4 a = *(const float4*)swp;
      float4 b = *(const float4*)(swp + 4);
      float vv[8] = {a.x * sc, a.y * sc, a.z * sc, a.w * sc,
                     b.x * sc, b.y * sc, b.z * sc, b.w * sc};
      int w0, w1; pack_fp8x8(vv, w0, w1);
      *(int2*)(wbt8 + (size_t)(o0 + o_l) * K2 + j0 + i_l * 8) = make_int2(w0, w1);
    }
  } else {
    // ---- per-row x prep: silu (bf16) + RBF bases (fp8) ----
    const int b = bx - 512;
    const float inv_sigma = 1.0f / sigma[0];
    const float* xrow = x + (size_t)b * IN_F;
    unsigned char* arow = Ab8 + (size_t)b * K2;
    __bf16* srow = sbA + (size_t)b * IN_F;
    {
      float4 v = ((const float4*)xrow)[t];
      float vv[4] = {v.x, v.y, v.z, v.w};
      union { __bf16 h[4]; uint2 q; } s;
      #pragma unroll
      for (int e = 0; e < 4; ++e) s.h[e] = (__bf16)(vv[e] / (1.0f + __expf(-vv[e])));
      ((uint2*)srow)[t] = s.q;
    }
    #pragma unroll
    for (int it = 0; it < 4; ++it) {
      const int i = t + it * 256;
      const float u = xrow[i];
      float4 g0 = *(const float4*)(grid + (size_t)i * GRID_N);
      float4 g1 = *(const float4*)(grid + (size_t)i * GRID_N + 4);
      float gg[8] = {g0.x, g0.y, g0.z, g0.w, g1.x, g1.y, g1.z, g1.w};
      float bb[8];
      #pragma unroll
      for (int g = 0; g < GRID_N; ++g) {
        float d = (u - gg[g]) * inv_sigma;
        bb[g] = __expf(-d * d);
      }
      int w0, w1; pack_fp8x8(bb, w0, w1);
      *(int2*)(arow + (size_t)i * GRID_N) = make_int2(w0, w1);
    }
  }
}

// ---------- launch 2: unified GEMM, fp8 phase (K=8192) + bf16 phase (K=1024) ----------
__global__ __launch_bounds__(256)
void kan_gemm_all(const unsigned char* __restrict__ Ab8,
                  const unsigned char* __restrict__ wbt8,
                  const __bf16* __restrict__ sbA,
                  const __bf16* __restrict__ sbT,
                  float* __restrict__ out) {
  __shared__ unsigned char As8[BM * BK8];   // 16 KB; bf16 phase aliases it
  __shared__ unsigned char Bs8[BN * BK8];   // 16 KB
  __bf16* As16 = (__bf16*)As8;
  __bf16* Bs16 = (__bf16*)Bs8;

  const int tid = threadIdx.x;
  const int bx  = blockIdx.x;
  const int s   = bx >> 3;
  const int r0  = ((bx & 7) * 8 + (s >> 3)) * BM;
  const int c0  = (s & 7) * BN;

  const int lane = tid & 63, wave = tid >> 6;
  const int wm = wave & 1, wn = wave >> 1;
  const int quad = lane >> 4, l15 = lane & 15;

  int a_off8[4][2], b_off8[4][2];
  #pragma unroll
  for (int t4 = 0; t4 < 4; ++t4) {
    const int rowA = wm * 64 + t4 * 16 + l15;
    const int rowB = wn * 64 + t4 * 16 + l15;
    #pragma unroll
    for (int h = 0; h < 2; ++h) {
      a_off8[t4][h] = rowA * BK8 + (((quad * 2 + h) ^ (rowA & 7)) * 16);
      b_off8[t4][h] = rowB * BK8 + (((quad * 2 + h) ^ (rowB & 7)) * 16);
    }
  }
  int a_off16[2][4], b_off16[2][4];
  #pragma unroll
  for (int ks = 0; ks < 2; ++ks) {
    const int kc = ks * 4 + quad;
    #pragma unroll
    for (int t4 = 0; t4 < 4; ++t4) {
      const int rowA = wm * 64 + t4 * 16 + l15;
      a_off16[ks][t4] = (rowA * 8 + (kc ^ (rowA & 7))) * 8;
      const int rowB = wn * 64 + t4 * 16 + l15;
      b_off16[ks][t4] = (rowB * 8 + (kc ^ (rowB & 7))) * 8;
    }
  }
  const unsigned char* aSrc8[4]; const unsigned char* bSrc8[4];
  const __bf16* aSrc16[4]; const __bf16* bSrc16[4]; int dstOff[4];
  #pragma unroll
  for (int it = 0; it < 4; ++it) {
    const int p = it * 256 + tid;
    const int row = p >> 3;
    const int kc  = (p & 7) ^ (row & 7);
    aSrc8[it]  = Ab8  + (size_t)(r0 + row) * K2 + kc * 16;
    bSrc8[it]  = wbt8 + (size_t)(c0 + row) * K2 + kc * 16;
    aSrc16[it] = sbA  + (size_t)(r0 + row) * IN_F + kc * 8;
    bSrc16[it] = sbT  + (size_t)(c0 + row) * IN_F + kc * 8;
    dstOff[it] = p * 16;
  }

  f32x4 zero; zero[0] = 0.f; zero[1] = 0.f; zero[2] = 0.f; zero[3] = 0.f;
  f32x4 acc[4][4];
  #pragma unroll
  for (int a = 0; a < 4; ++a)
    #pragma unroll
    for (int b = 0; b < 4; ++b) acc[a][b] = zero;

  // ---- phase 1: fp8 MX spline, 64 iters ----
  for (int kb = 0; kb < K2; kb += BK8) {
    __syncthreads();
    #pragma unroll
    for (int it = 0; it < 4; ++it) {
      gl2lds16(aSrc8[it] + kb, &As8[dstOff[it]]);
      gl2lds16(bSrc8[it] + kb, &Bs8[dstOff[it]]);
    }
    __syncthreads();
    union frag { int32x8 v; uint4 q[2]; };
    frag af[4], bfv[4];
    #pragma unroll
    for (int t4 = 0; t4 < 4; ++t4) {
      af[t4].q[0]  = *(const uint4*)&As8[a_off8[t4][0]];
      af[t4].q[1]  = *(const uint4*)&As8[a_off8[t4][1]];
      bfv[t4].q[0] = *(const uint4*)&Bs8[b_off8[t4][0]];
      bfv[t4].q[1] = *(const uint4*)&Bs8[b_off8[t4][1]];
    }
    #pragma unroll
    for (int tm = 0; tm < 4; ++tm)
      #pragma unroll
      for (int tn = 0; tn < 4; ++tn)
        acc[tm][tn] = __builtin_amdgcn_mfma_scale_f32_16x16x128_f8f6f4(
            af[tm].v, bfv[tn].v, acc[tm][tn],
            0, 0, 0, 0x7F7F7F7F, 0, 0x7F7F7F7F);
  }

  // ---- phase 2: bf16 base, 16 iters (same acc) ----
  for (int kb = 0; kb < IN_F; kb += BK) {
    __syncthreads();
    #pragma unroll
    for (int it = 0; it < 4; ++it) {
      gl2lds16(aSrc16[it] + kb, (char*)As16 + dstOff[it]);
      gl2lds16(bSrc16[it] + kb, (char*)Bs16 + dstOff[it]);
    }
    __syncthreads();
    #pragma unroll
    for (int ks = 0; ks < 2; ++ks) {
      bf16x8 af[4], bfv[4];
      #pragma unroll
      for (int t4 = 0; t4 < 4; ++t4) af[t4]  = *(const bf16x8*)&As16[a_off16[ks][t4]];
      #pragma unroll
      for (int t4 = 0; t4 < 4; ++t4) bfv[t4] = *(const bf16x8*)&Bs16[b_off16[ks][t4]];
      #pragma unroll
      for (int tm = 0; tm < 4; ++tm)
        #pragma unroll
        for (int tn = 0; tn < 4; ++tn)
          acc[tm][tn] = __builtin_amdgcn_mfma_f32_16x16x32_bf16(
              af[tm], bfv[tn], acc[tm][tn], 0, 0, 0);
    }
  }

  // ---- epilogue: plain store ----
  #pragma unroll
  for (int tm = 0; tm < 4; ++tm) {
    const int row = r0 + wm * 64 + tm * 16 + quad * 4;
    #pragma unroll
    for (int tn = 0; tn < 4; ++tn) {
      const int col = c0 + wn * 64 + tn * 16 + l15;
      float* op = out + (size_t)row * OUT_F + col;
      #pragma unroll
      for (int r = 0; r < 4; ++r)
        op[(size_t)r * OUT_F] = acc[tm][tn][r];
    }
  }
}

// ---------- fallback path (ws too small): full-W bf16 prep + fused gemm ----------
__global__ __launch_bounds__(256)
void kan_prep_w_full(const float* __restrict__ sb, const float* __restrict__ sw,
                     const float* __restrict__ ss, __bf16* __restrict__ wbt) {
  const int t = threadIdx.x;
  if (blockIdx.x < 256) {
    __shared__ float tile[64][65];
    const int o0 = (blockIdx.x & 15) * 64, k0 = (blockIdx.x >> 4) * 64;
    const int r = t >> 4, c4 = (t & 15) * 4;
    #pragma unroll
    for (int it = 0; it < 4; ++it) {
      const int k = k0 + r + it * 16;
      float4 v = *(const float4*)(sb + (size_t)k * OUT_F + o0 + c4);
      tile[r + it * 16][c4 + 0] = v.x; tile[r + it * 16][c4 + 1] = v.y;
      tile[r + it * 16][c4 + 2] = v.z; tile[r + it * 16][c4 + 3] = v.w;
    }
    __syncthreads();
    #pragma unroll
    for (int it = 0; it < 4; ++it) {
      const int ol = r + it * 16;
      union { __bf16 h[4]; uint2 q; } s;
      #pragma unroll
      for (int e = 0; e < 4; ++e) s.h[e] = (__bf16)tile[c4 + e][ol];
      *(uint2*)(wbt + (size_t)(o0 + ol) * KTOT + k0 + c4) = s.q;
    }
  } else {
    const size_t e = ((size_t)(blockIdx.x - 256) * 256 + t) * 8;
    const int o = (int)(e >> 13);
    const int j = (int)(e & 8191);
    const int i = j >> 3;
    const float sc = ss[(size_t)i * OUT_F + o];
    float4 a = *(const float4*)(sw + e);
    float4 b = *(const float4*)(sw + e + 4);
    float vv[8] = {a.x, a.y, a.z, a.w, b.x, b.y, b.z, b.w};
    union { __bf16 h[8]; uint4 q; } s;
    #pragma unroll
    for (int g = 0; g < 8; ++g) s.h[g] = (__bf16)(vv[g] * sc);
    *(uint4*)(wbt + (size_t)o * KTOT + IN_F + j) = s.q;
  }
}

__global__ __launch_bounds__(256, 2)
void kan_gemm_fused(const float* __restrict__ x, const __bf16* __restrict__ wbt,
                    const float* __restrict__ grid, const float* __restrict__ sigma,
                    float* __restrict__ out) {
  __shared__ __bf16 As[BM * BK];
  __shared__ __bf16 Bs[BN * BK];
  __shared__ float  gLds[IN_F * GRID_N];
  const int tid = threadIdx.x;
  const int bx  = blockIdx.x;
  const int c0  = (bx & 7) * BN;
  const int r0  = (bx >> 3) * BM;
  for (int idx = tid; idx < IN_F * GRID_N / 4; idx += 256)
    ((float4*)gLds)[idx] = ((const float4*)grid)[idx];
  const float inv_sigma = 1.0f / sigma[0];
  const int lane = tid & 63, wave = tid >> 6;
  const int wm = wave & 1, wn = wave >> 1;
  const int quad = lane >> 4, l15 = lane & 15;
  f32x4 zero; zero[0] = 0.f; zero[1] = 0.f; zero[2] = 0.f; zero[3] = 0.f;
  f32x4 acc[4][4];
  #pragma unroll
  for (int a = 0; a < 4; ++a)
    #pragma unroll
    for (int b = 0; b < 4; ++b) acc[a][b] = zero;
  const int m = tid >> 1, half = tid & 1;
  const float* xrow = x + (size_t)(r0 + m) * IN_F;
  __syncthreads();
  for (int kb = 0; kb < KTOT; kb += BK) {
    union { __bf16 h[32]; uint4 q[4]; } av;
    if (kb < IN_F) {
      const float4* xp = (const float4*)(xrow + kb + half * 32);
      #pragma unroll
      for (int j4 = 0; j4 < 8; ++j4) {
        float4 v = xp[j4];
        float vv[4] = {v.x, v.y, v.z, v.w};
        #pragma unroll
        for (int e = 0; e < 4; ++e)
          av.h[j4 * 4 + e] = (__bf16)(vv[e] / (1.0f + __expf(-vv[e])));
      }
    } else {
      const int i0 = (kb - IN_F) >> 3;
      float4 xv = *(const float4*)(xrow + i0 + half * 4);
      float xs[4] = {xv.x, xv.y, xv.z, xv.w};
      #pragma unroll
      for (int ii = 0; ii < 4; ++ii) {
        const float u = xs[ii];
        const float* gp = &gLds[(i0 + half * 4 + ii) * GRID_N];
        #pragma unroll
        for (int g = 0; g < GRID_N; ++g) {
          float d = (u - gp[g]) * inv_sigma;
          av.h[ii * 8 + g] = (__bf16)__expf(-d * d);
        }
      }
    }
    __syncthreads();
    {
      uint4* dst = (uint4*)&As[m * BK + half * 32];
      #pragma unroll
      for (int qd = 0; qd < 4; ++qd) dst[qd] = av.q[qd];
    }
    #pragma unroll
    for (int it = 0; it < 4; ++it) {
      const int idx = it * 2048 + tid * 8;
      const int n = idx >> 6, k = idx & 63;
      gl2lds16(wbt + (size_t)(c0 + n) * KTOT + kb + k, &Bs[idx]);
    }
    __syncthreads();
    #pragma unroll
    for (int ks = 0; ks < 2; ++ks) {
      bf16x8 af[4], bfv[4];
      #pragma unroll
      for (int t4 = 0; t4 < 4; ++t4)
        af[t4] = *(const bf16x8*)&As[(wm * 64 + t4 * 16 + l15) * BK + ks * 32 + quad * 8];
      #pragma unroll
      for (int t4 = 0; t4 < 4; ++t4)
        bfv[t4] = *(const bf16x8*)&Bs[(wn * 64 + t4 * 16 + l15) * BK + ks * 32 + quad * 8];
      #pragma unroll
      for (int tm = 0; tm < 4; ++tm)
        #pragma unroll
        for (int tn = 0; tn < 4; ++tn)
          acc[tm][tn] = __builtin_amdgcn_mfma_f32_16x16x32_bf16(
              af[tm], bfv[tn], acc[tm][tn], 0, 0, 0);
    }
  }
  #pragma unroll
  for (int tm = 0; tm < 4; ++tm) {
    const int row = r0 + wm * 64 + tm * 16 + quad * 4;
    #pragma unroll
    for (int tn = 0; tn < 4; ++tn) {
      const int col = c0 + wn * 64 + tn * 16 + l15;
      float* op = out + (size_t)row * OUT_F + col;
      #pragma unroll
      for (int r = 0; r < 4; ++r)
        op[(size_t)r * OUT_F] = acc[tm][tn][r];
    }
  }
}

extern "C" void kernel_launch(void* const* d_in, const int* in_sizes, int n_in,
                              void* d_out, int out_size, void* d_ws, size_t ws_size,
                              hipStream_t stream) {
  const float* x     = (const float*)d_in[0];
  const float* sb    = (const float*)d_in[1];
  const float* sw    = (const float*)d_in[2];
  const float* ss    = (const float*)d_in[3];
  const float* grid  = (const float*)d_in[4];
  const float* sigma = (const float*)d_in[5];
  float* out = (float*)d_out;

  const size_t SBT_BYTES = (size_t)OUT_F * IN_F * 2;   //   2 MB (bf16)
  const size_t WS_BYTES  = (size_t)OUT_F * K2;         //  8.4 MB (fp8)
  const size_t A_BYTES   = (size_t)BATCH * K2;         // 67.1 MB (fp8)
  const size_t SBA_BYTES = (size_t)BATCH * IN_F * 2;   // 16.8 MB (bf16)

  if (ws_size >= SBT_BYTES + WS_BYTES + A_BYTES + SBA_BYTES) {
    __bf16*        sbT  = (__bf16*)d_ws;
    unsigned char* wbt8 = (unsigned char*)d_ws + SBT_BYTES;
    unsigned char* Ab8  = (unsigned char*)d_ws + SBT_BYTES + WS_BYTES;
    __bf16*        sbA  = (__bf16*)((char*)d_ws + SBT_BYTES + WS_BYTES + A_BYTES);
    kan_mix<<<dim3(512 + BATCH), dim3(256), 0, stream>>>(
        x, sb, sw, ss, grid, sigma, sbT, wbt8, Ab8, sbA);
    kan_gemm_all<<<dim3((BATCH / BM) * (OUT_F / BN)), dim3(256), 0, stream>>>(
        Ab8, wbt8, sbA, sbT, out);
  } else {
    __bf16* wbt = (__bf16*)d_ws;   // 18.9 MB
    kan_prep_w_full<<<dim3(4352), dim3(256), 0, stream>>>(sb, sw, ss, wbt);
    kan_gemm_fused<<<dim3((BATCH / BM) * (OUT_F / BN)), dim3(256), 0, stream>>>(
        x, wbt, grid, sigma, out);
  }
}